// Round 3
// baseline (2899.553 us; speedup 1.0000x reference)
//
#include <hip/hip_runtime.h>
#include <hip/hip_bf16.h>
#include <math.h>

#define BB 4
#define SS 2048
#define DIN 768
#define HH 12
#define DH 64

// ---------- bf16 helpers (bit-level, fast) ----------
__device__ inline unsigned short f2bf(float f) {
    unsigned int u = __float_as_uint(f);
    unsigned int lsb = (u >> 16) & 1u;
    u += 0x7fffu + lsb;           // round-to-nearest-even
    return (unsigned short)(u >> 16);
}
__device__ inline void unpack8(uint4 u, float* f) {
    f[0] = __uint_as_float(u.x << 16); f[1] = __uint_as_float(u.x & 0xffff0000u);
    f[2] = __uint_as_float(u.y << 16); f[3] = __uint_as_float(u.y & 0xffff0000u);
    f[4] = __uint_as_float(u.z << 16); f[5] = __uint_as_float(u.z & 0xffff0000u);
    f[6] = __uint_as_float(u.w << 16); f[7] = __uint_as_float(u.w & 0xffff0000u);
}

// ---------------------------------------------------------------
// Kernel 1: per-head QKV projection.  x[8192][768] fp32 ×
// W[h][768][64] fp32 -> Q,K fp32 / V bf16 in [B][H][S][64] layout.
// grid = (128 m-tiles, 12 heads, 3 {q,k,v}), block = 256.
// Q/K kept fp32: bf16 scores perturb near-tie softmax rows
// (score std=256, top-2 gap ~Exp(65); bf16 err +-1.5 flipped
// ~2% of rows -> absmax 832 in round 2).
// ---------------------------------------------------------------
__global__ __launch_bounds__(256) void qkv_proj_kernel(
    const float* __restrict__ x,
    const float* __restrict__ wq,
    const float* __restrict__ wk,
    const float* __restrict__ wv,
    float* __restrict__ qf,
    float* __restrict__ kf,
    unsigned short* __restrict__ vb)
{
    const int mt = blockIdx.x;
    const int h  = blockIdx.y;
    const int which = blockIdx.z;
    const float* w = (which == 0) ? wq : (which == 1) ? wk : wv;
    w += (size_t)h * (DIN * DH);

    __shared__ float xs[64][17];   // 64 rows x 16 k, pad
    __shared__ float wt[16][65];   // 16 k x 64 cols, pad

    const int t  = threadIdx.x;
    const int m0 = mt * 64;
    const int tr = t >> 4, tc = t & 15;

    float acc[4][4] = {};

    for (int k0 = 0; k0 < DIN; k0 += 16) {
        {   // x tile: 4 threads per row, float4 each
            int r = t >> 2, c4 = (t & 3) * 4;
            float4 v = *reinterpret_cast<const float4*>(x + (size_t)(m0 + r) * DIN + k0 + c4);
            xs[r][c4 + 0] = v.x; xs[r][c4 + 1] = v.y; xs[r][c4 + 2] = v.z; xs[r][c4 + 3] = v.w;
        }
        {   // w tile: 16 threads per k-row, float4 each
            int kk = t >> 4, c4 = (t & 15) * 4;
            float4 v = *reinterpret_cast<const float4*>(w + (size_t)(k0 + kk) * DH + c4);
            wt[kk][c4 + 0] = v.x; wt[kk][c4 + 1] = v.y; wt[kk][c4 + 2] = v.z; wt[kk][c4 + 3] = v.w;
        }
        __syncthreads();
        #pragma unroll
        for (int kk = 0; kk < 16; ++kk) {
            float a[4], b[4];
            #pragma unroll
            for (int i = 0; i < 4; ++i) a[i] = xs[tr * 4 + i][kk];
            #pragma unroll
            for (int j = 0; j < 4; ++j) b[j] = wt[kk][tc * 4 + j];
            #pragma unroll
            for (int i = 0; i < 4; ++i)
                #pragma unroll
                for (int j = 0; j < 4; ++j)
                    acc[i][j] = fmaf(a[i], b[j], acc[i][j]);
        }
        __syncthreads();
    }

    #pragma unroll
    for (int i = 0; i < 4; ++i) {
        int m = m0 + tr * 4 + i;
        int b = m >> 11, s = m & 2047;
        size_t base = (((size_t)(b * HH + h)) * SS + s) * DH + tc * 4;
        if (which < 2) {
            float* outf = (which == 0) ? qf : kf;
            #pragma unroll
            for (int j = 0; j < 4; ++j) outf[base + j] = acc[i][j];
        } else {
            #pragma unroll
            for (int j = 0; j < 4; ++j) vb[base + j] = f2bf(acc[i][j]);
        }
    }
}

// ---------------------------------------------------------------
// Kernel 2: flash-style attention per (b, h, 64-row q-tile).
// Q/K fp32 (exact scores), V bf16. Online softmax; K/V in 32-row
// LDS tiles; O accumulator in regs.
// grid = (32 q-tiles, 12 heads, 4 batch), block = 256.
// z written as [B][S][H*64] bf16 (matches reference transpose).
// ---------------------------------------------------------------
__global__ __launch_bounds__(256) void attn_kernel(
    const float* __restrict__ qf,
    const float* __restrict__ kf,
    const unsigned short* __restrict__ vb,
    unsigned short* __restrict__ z)
{
    const int qt = blockIdx.x, h = blockIdx.y, b = blockIdx.z;
    const size_t headbase = (((size_t)b * HH + h)) * SS * DH;
    const float* Q = qf + headbase;
    const float* K = kf + headbase;
    const unsigned short* V = vb + headbase;

    __shared__ float qs[64][65];
    __shared__ float ks[32][65];
    __shared__ float vs[32][65];
    __shared__ float ps[64][33];
    __shared__ float mrun[64], lrun[64], scal[64];

    const int t = threadIdx.x;

    {   // Q tile -> LDS fp32: thread owns 16 consecutive floats
        int r = t >> 2, c0 = (t & 3) * 16;
        const float4* src = reinterpret_cast<const float4*>(Q + (size_t)(qt * 64 + r) * DH + c0);
        #pragma unroll
        for (int q4 = 0; q4 < 4; ++q4) {
            float4 v = src[q4];
            qs[r][c0 + q4 * 4 + 0] = v.x; qs[r][c0 + q4 * 4 + 1] = v.y;
            qs[r][c0 + q4 * 4 + 2] = v.z; qs[r][c0 + q4 * 4 + 3] = v.w;
        }
    }
    if (t < 64) { mrun[t] = -INFINITY; lrun[t] = 0.0f; }

    float o[16];
    #pragma unroll
    for (int c = 0; c < 16; ++c) o[c] = 0.0f;
    const int orow = t >> 2, oc0 = (t & 3) * 16;
    const float sc = 0.125f;   // 1/sqrt(64)

    for (int kt = 0; kt < SS / 32; ++kt) {
        __syncthreads();   // covers initial writes, protects ks/vs reuse
        {   // K (fp32) / V (bf16) 32-row tiles -> LDS fp32
            int r = t >> 3, c0 = (t & 7) * 8;
            const float4* ksrc = reinterpret_cast<const float4*>(K + (size_t)(kt * 32 + r) * DH + c0);
            float4 k0v = ksrc[0], k1v = ksrc[1];
            ks[r][c0 + 0] = k0v.x; ks[r][c0 + 1] = k0v.y; ks[r][c0 + 2] = k0v.z; ks[r][c0 + 3] = k0v.w;
            ks[r][c0 + 4] = k1v.x; ks[r][c0 + 5] = k1v.y; ks[r][c0 + 6] = k1v.z; ks[r][c0 + 7] = k1v.w;
            uint4 vu = *reinterpret_cast<const uint4*>(V + (size_t)(kt * 32 + r) * DH + c0);
            float f[8];
            unpack8(vu, f);
            #pragma unroll
            for (int c = 0; c < 8; ++c) vs[r][c0 + c] = f[c];
        }
        __syncthreads();

        {   // scores: thread owns 4 rows x 2 cols
            int r0 = (t >> 4) * 4, c0s = (t & 15) * 2;
            float d[4][2] = {};
            #pragma unroll 8
            for (int kk = 0; kk < 64; ++kk) {
                float a0 = qs[r0 + 0][kk], a1 = qs[r0 + 1][kk];
                float a2 = qs[r0 + 2][kk], a3 = qs[r0 + 3][kk];
                float e0 = ks[c0s + 0][kk], e1 = ks[c0s + 1][kk];
                d[0][0] = fmaf(a0, e0, d[0][0]); d[0][1] = fmaf(a0, e1, d[0][1]);
                d[1][0] = fmaf(a1, e0, d[1][0]); d[1][1] = fmaf(a1, e1, d[1][1]);
                d[2][0] = fmaf(a2, e0, d[2][0]); d[2][1] = fmaf(a2, e1, d[2][1]);
                d[3][0] = fmaf(a3, e0, d[3][0]); d[3][1] = fmaf(a3, e1, d[3][1]);
            }
            #pragma unroll
            for (int i = 0; i < 4; ++i)
                #pragma unroll
                for (int j = 0; j < 2; ++j)
                    ps[r0 + i][c0s + j] = d[i][j] * sc;
        }
        __syncthreads();

        if (t < 64) {   // online softmax row update
            float mx = ps[t][0];
            #pragma unroll
            for (int j = 1; j < 32; ++j) mx = fmaxf(mx, ps[t][j]);
            float newm = fmaxf(mrun[t], mx);
            float corr = __expf(mrun[t] - newm);
            float sum = 0.0f;
            #pragma unroll
            for (int j = 0; j < 32; ++j) {
                float p = __expf(ps[t][j] - newm);
                ps[t][j] = p;
                sum += p;
            }
            lrun[t] = lrun[t] * corr + sum;
            mrun[t] = newm;
            scal[t] = corr;
        }
        __syncthreads();

        {   // O update: thread owns (orow, 16 cols)
            float corr = scal[orow];
            #pragma unroll
            for (int c = 0; c < 16; ++c) o[c] *= corr;
            for (int j = 0; j < 32; ++j) {
                float p = ps[orow][j];
                #pragma unroll
                for (int c = 0; c < 16; ++c)
                    o[c] = fmaf(p, vs[j][oc0 + c], o[c]);
            }
        }
    }

    float inv = 1.0f / lrun[orow];
    size_t zb = ((size_t)b * SS + qt * 64 + orow) * (size_t)(HH * DH) + h * DH + oc0;
    #pragma unroll
    for (int c = 0; c < 16; ++c) z[zb + c] = f2bf(o[c] * inv);
}

// ---------------------------------------------------------------
// Kernel 3: out[m][i] = sum_j wc[i][j] * z[m][j]
// z [8192][768] bf16, wc [64][768] fp32 -> out [8192][64] fp32
// grid = 128 m-tiles, block = 256.
// ---------------------------------------------------------------
__global__ __launch_bounds__(256) void outproj_kernel(
    const unsigned short* __restrict__ z,
    const float* __restrict__ wc,
    float* __restrict__ out)
{
    const int mt = blockIdx.x;
    __shared__ float zs[64][17];
    __shared__ float wcs[64][17];

    const int t  = threadIdx.x;
    const int m0 = mt * 64;
    const int tr = t >> 4, tc = t & 15;

    float acc[4][4] = {};

    for (int k0 = 0; k0 < DIN; k0 += 16) {
        {   // z tile (bf16): 4 threads/row, 4 elems each
            int r = t >> 2, c4 = (t & 3) * 4;
            uint2 u = *reinterpret_cast<const uint2*>(z + (size_t)(m0 + r) * DIN + k0 + c4);
            zs[r][c4 + 0] = __uint_as_float(u.x << 16);
            zs[r][c4 + 1] = __uint_as_float(u.x & 0xffff0000u);
            zs[r][c4 + 2] = __uint_as_float(u.y << 16);
            zs[r][c4 + 3] = __uint_as_float(u.y & 0xffff0000u);
        }
        {   // wc tile: wcs[i][jj] = wc[i][k0+jj]
            int i = t >> 2, c4 = (t & 3) * 4;
            float4 v = *reinterpret_cast<const float4*>(wc + (size_t)i * DIN + k0 + c4);
            wcs[i][c4 + 0] = v.x; wcs[i][c4 + 1] = v.y; wcs[i][c4 + 2] = v.z; wcs[i][c4 + 3] = v.w;
        }
        __syncthreads();
        #pragma unroll
        for (int kk = 0; kk < 16; ++kk) {
            float a[4], b[4];
            #pragma unroll
            for (int i = 0; i < 4; ++i) a[i] = zs[tr * 4 + i][kk];
            #pragma unroll
            for (int j = 0; j < 4; ++j) b[j] = wcs[tc * 4 + j][kk];
            #pragma unroll
            for (int i = 0; i < 4; ++i)
                #pragma unroll
                for (int j = 0; j < 4; ++j)
                    acc[i][j] = fmaf(a[i], b[j], acc[i][j]);
        }
        __syncthreads();
    }

    #pragma unroll
    for (int i = 0; i < 4; ++i) {
        float4 v = make_float4(acc[i][0], acc[i][1], acc[i][2], acc[i][3]);
        *reinterpret_cast<float4*>(out + (size_t)(m0 + tr * 4 + i) * DH + tc * 4) = v;
    }
}

extern "C" void kernel_launch(void* const* d_in, const int* in_sizes, int n_in,
                              void* d_out, int out_size, void* d_ws, size_t ws_size,
                              hipStream_t stream) {
    const float* x  = (const float*)d_in[0];
    const float* wq = (const float*)d_in[1];
    const float* wk = (const float*)d_in[2];
    const float* wv = (const float*)d_in[3];
    const float* wc = (const float*)d_in[4];
    float* out = (float*)d_out;

    // workspace layout (75.5 MB):
    //   Q fp32 [B][H][S][64]  (25.2 MB)
    //   K fp32 [B][H][S][64]  (25.2 MB)
    //   V bf16 [B][H][S][64]  (12.6 MB)
    //   Z bf16 [B][S][H*64]   (12.6 MB)
    const size_t plane = (size_t)BB * HH * SS * DH;   // 6291456
    float* qfp = (float*)d_ws;
    float* kfp = qfp + plane;
    unsigned short* vb = (unsigned short*)(kfp + plane);
    unsigned short* zb = vb + plane;

    dim3 g1(128, HH, 3);
    qkv_proj_kernel<<<g1, 256, 0, stream>>>(x, wq, wk, wv, qfp, kfp, vb);
    dim3 g2(SS / 64, HH, BB);
    attn_kernel<<<g2, 256, 0, stream>>>(qfp, kfp, vb, zb);
    outproj_kernel<<<128, 256, 0, stream>>>(zb, wc, out);
}

// Round 4
// 445.496 us; speedup vs baseline: 6.5086x; 6.5086x over previous
//
#include <hip/hip_runtime.h>
#include <hip/hip_bf16.h>
#include <math.h>

#define BB 4
#define SS 2048
#define DIN 768
#define HH 12
#define DH 64

typedef __attribute__((ext_vector_type(8))) short bf16x8;
typedef __attribute__((ext_vector_type(4))) float f32x4;

// ---------- bf16 helpers ----------
__device__ inline unsigned short f2bf(float f) {
    unsigned int u = __float_as_uint(f);
    u += 0x7fffu + ((u >> 16) & 1u);      // round-to-nearest-even
    return (unsigned short)(u >> 16);
}
__device__ inline float bf2f(unsigned short h) {
    return __uint_as_float(((unsigned int)h) << 16);
}
// split fp32 into bf16 hi + bf16 lo (v ~= hi + lo to ~2^-17 rel)
__device__ inline void splitf(float v, unsigned short& hi, unsigned short& lo) {
    hi = f2bf(v);
    lo = f2bf(v - bf2f(hi));
}
__device__ inline uint4 pack8(const unsigned short* s) {
    uint4 u;
    u.x = (unsigned)s[0] | ((unsigned)s[1] << 16);
    u.y = (unsigned)s[2] | ((unsigned)s[3] << 16);
    u.z = (unsigned)s[4] | ((unsigned)s[5] << 16);
    u.w = (unsigned)s[6] | ((unsigned)s[7] << 16);
    return u;
}

// ---------------------------------------------------------------
// prep_w: W[h][k][n] fp32 -> transposed+split planes whi/wlo[(which,h)][n][k] bf16
// grid (12 ktiles, 12 h, 3 which), block 256
// ---------------------------------------------------------------
__global__ __launch_bounds__(256) void prep_w_kernel(
    const float* __restrict__ wq, const float* __restrict__ wk, const float* __restrict__ wv,
    unsigned short* __restrict__ whi, unsigned short* __restrict__ wlo)
{
    const int kt = blockIdx.x, h = blockIdx.y, which = blockIdx.z;
    const float* w = (which == 0) ? wq : (which == 1) ? wk : wv;
    w += (size_t)h * (DIN * DH);
    const size_t plane = ((size_t)which * HH + h) * (size_t)(64 * DIN);

    __shared__ float tile[64][65];
    const int t = threadIdx.x;
    {
        int r = t >> 2, n0 = (t & 3) * 16;
        const float* src = w + (size_t)(kt * 64 + r) * DH + n0;
        #pragma unroll
        for (int q = 0; q < 4; ++q) {
            float4 v = *reinterpret_cast<const float4*>(src + q * 4);
            tile[r][n0 + q * 4 + 0] = v.x; tile[r][n0 + q * 4 + 1] = v.y;
            tile[r][n0 + q * 4 + 2] = v.z; tile[r][n0 + q * 4 + 3] = v.w;
        }
    }
    __syncthreads();
    {
        int n = t >> 2, k0 = (t & 3) * 16;
        unsigned short hi16[16], lo16[16];
        #pragma unroll
        for (int j = 0; j < 16; ++j) splitf(tile[k0 + j][n], hi16[j], lo16[j]);
        size_t base = plane + (size_t)n * DIN + kt * 64 + k0;
        *reinterpret_cast<uint4*>(whi + base)     = pack8(hi16);
        *reinterpret_cast<uint4*>(whi + base + 8) = pack8(hi16 + 8);
        *reinterpret_cast<uint4*>(wlo + base)     = pack8(lo16);
        *reinterpret_cast<uint4*>(wlo + base + 8) = pack8(lo16 + 8);
    }
}

// prep_wc: wc [64][768] fp32 -> wch/wcl bf16 (same layout). grid 24, block 256.
__global__ __launch_bounds__(256) void prep_wc_kernel(
    const float* __restrict__ wc,
    unsigned short* __restrict__ wch, unsigned short* __restrict__ wcl)
{
    int idx = (blockIdx.x * 256 + threadIdx.x) * 8;
    float4 a = *reinterpret_cast<const float4*>(wc + idx);
    float4 b = *reinterpret_cast<const float4*>(wc + idx + 4);
    float f[8] = {a.x, a.y, a.z, a.w, b.x, b.y, b.z, b.w};
    unsigned short h8[8], l8[8];
    #pragma unroll
    for (int j = 0; j < 8; ++j) splitf(f[j], h8[j], l8[j]);
    *reinterpret_cast<uint4*>(wch + idx) = pack8(h8);
    *reinterpret_cast<uint4*>(wcl + idx) = pack8(l8);
}

// ---------------------------------------------------------------
// qkv_proj: x fp32 [8192][768] x Wsplit -> Qh/Ql/Kh/Kl/V bf16 [b][h][s][64]
// 3-term split MFMA (xh*wh + xh*wl + xl*wh). grid (40, 128): bx%8 pins
// the (which,h) weight plane to one XCD (40%8==0); bx>=36 idles.
// ---------------------------------------------------------------
__global__ __launch_bounds__(256) void qkv_proj_kernel(
    const float* __restrict__ x,
    const unsigned short* __restrict__ whi, const unsigned short* __restrict__ wlo,
    unsigned short* __restrict__ qh, unsigned short* __restrict__ ql,
    unsigned short* __restrict__ kh, unsigned short* __restrict__ kl,
    unsigned short* __restrict__ vv)
{
    const int hw = blockIdx.x;
    if (hw >= 36) return;
    const int which = hw / HH, h = hw % HH;
    const int mt = blockIdx.y;
    const int m0 = mt * 64;
    const size_t plane = ((size_t)which * HH + h) * (size_t)(64 * DIN);

    __shared__ unsigned short xsh[64][40], xsl[64][40], wsh[64][40], wsl[64][40];

    const int t = threadIdx.x;
    const int lane = t & 63, wid = t >> 6;
    const int fr = lane & 15, fg = lane >> 4, g8 = fg * 8;

    f32x4 acc[4];
    #pragma unroll
    for (int n = 0; n < 4; ++n) acc[n] = (f32x4){0.f, 0.f, 0.f, 0.f};

    for (int ks = 0; ks < DIN / 32; ++ks) {
        const int k0 = ks * 32;
        {   // stage x tile (split on the fly)
            int r = t >> 2, c8 = (t & 3) * 8;
            const float* xp = x + (size_t)(m0 + r) * DIN + k0 + c8;
            float4 a = *reinterpret_cast<const float4*>(xp);
            float4 b = *reinterpret_cast<const float4*>(xp + 4);
            float f[8] = {a.x, a.y, a.z, a.w, b.x, b.y, b.z, b.w};
            unsigned short h8[8], l8[8];
            #pragma unroll
            for (int j = 0; j < 8; ++j) splitf(f[j], h8[j], l8[j]);
            *reinterpret_cast<uint4*>(&xsh[r][c8]) = pack8(h8);
            *reinterpret_cast<uint4*>(&xsl[r][c8]) = pack8(l8);
            // stage W tiles (already bf16, [n][k] layout)
            size_t wb = plane + (size_t)r * DIN + k0 + c8;
            *reinterpret_cast<uint4*>(&wsh[r][c8]) = *reinterpret_cast<const uint4*>(whi + wb);
            *reinterpret_cast<uint4*>(&wsl[r][c8]) = *reinterpret_cast<const uint4*>(wlo + wb);
        }
        __syncthreads();
        bf16x8 ah = *reinterpret_cast<const bf16x8*>(&xsh[wid * 16 + fr][g8]);
        bf16x8 al = *reinterpret_cast<const bf16x8*>(&xsl[wid * 16 + fr][g8]);
        #pragma unroll
        for (int n = 0; n < 4; ++n) {
            bf16x8 bh = *reinterpret_cast<const bf16x8*>(&wsh[n * 16 + fr][g8]);
            bf16x8 bl = *reinterpret_cast<const bf16x8*>(&wsl[n * 16 + fr][g8]);
            acc[n] = __builtin_amdgcn_mfma_f32_16x16x32_bf16(ah, bh, acc[n], 0, 0, 0);
            acc[n] = __builtin_amdgcn_mfma_f32_16x16x32_bf16(ah, bl, acc[n], 0, 0, 0);
            acc[n] = __builtin_amdgcn_mfma_f32_16x16x32_bf16(al, bh, acc[n], 0, 0, 0);
        }
        __syncthreads();
    }

    // epilogue: C layout col=lane&15, row=(lane>>4)*4+reg
    #pragma unroll
    for (int n = 0; n < 4; ++n) {
        #pragma unroll
        for (int j = 0; j < 4; ++j) {
            int row = wid * 16 + fg * 4 + j;
            int m = m0 + row, b = m >> 11, s = m & 2047;
            size_t idx = (((size_t)b * HH + h) * SS + s) * DH + n * 16 + fr;
            float val = acc[n][j];
            if (which == 0) { unsigned short hi, lo; splitf(val, hi, lo); qh[idx] = hi; ql[idx] = lo; }
            else if (which == 1) { unsigned short hi, lo; splitf(val, hi, lo); kh[idx] = hi; kl[idx] = lo; }
            else vv[idx] = f2bf(val);
        }
    }
}

// ---------------------------------------------------------------
// attn: flash MFMA. 64 q-rows/block, 4 waves x 16 rows, KV tiles of 64.
// QK^T = qh*kh + qh*kl + ql*kh (fp32-grade scores); softmax in-register;
// P via fp32 LDS (wave-private); V transposed in LDS for B operand.
// grid 1536 flat, XCD-chunk swizzled. z out [b][s][768] bf16.
// ---------------------------------------------------------------
__global__ __launch_bounds__(256) void attn_kernel(
    const unsigned short* __restrict__ qhp, const unsigned short* __restrict__ qlp,
    const unsigned short* __restrict__ khp, const unsigned short* __restrict__ klp,
    const unsigned short* __restrict__ vvp,
    unsigned short* __restrict__ z)
{
    // bijective XCD-chunk swizzle: same (b,h) q-tiles share an XCD L2
    const int flat = blockIdx.x;
    const int remap = (flat & 7) * 192 + (flat >> 3);
    const int qt = remap & 31;
    const int h  = (remap >> 5) % HH;
    const int b  = remap / (32 * HH);

    const size_t headbase = ((size_t)b * HH + h) * (size_t)(SS * DH);
    const unsigned short* Qh = qhp + headbase;
    const unsigned short* Ql = qlp + headbase;
    const unsigned short* Kh = khp + headbase;
    const unsigned short* Kl = klp + headbase;
    const unsigned short* Vv = vvp + headbase;

    __shared__ unsigned short qsh[64][72], qsl[64][72];
    __shared__ unsigned short ksh[64][72], ksl[64][72];
    __shared__ unsigned short vts[64][72];       // V transposed: [d][k]
    __shared__ float ps[64][68];                 // P fp32 (wave-private rows)

    const int t = threadIdx.x;
    const int lane = t & 63, wid = t >> 6;
    const int fr = lane & 15, fg = lane >> 4, g8 = fg * 8;

    {   // stage Q (once)
        int r = t >> 2, c0 = (t & 3) * 16;
        size_t srcb = (size_t)(qt * 64 + r) * DH + c0;
        *reinterpret_cast<uint4*>(&qsh[r][c0])     = *reinterpret_cast<const uint4*>(Qh + srcb);
        *reinterpret_cast<uint4*>(&qsh[r][c0 + 8]) = *reinterpret_cast<const uint4*>(Qh + srcb + 8);
        *reinterpret_cast<uint4*>(&qsl[r][c0])     = *reinterpret_cast<const uint4*>(Ql + srcb);
        *reinterpret_cast<uint4*>(&qsl[r][c0 + 8]) = *reinterpret_cast<const uint4*>(Ql + srcb + 8);
    }

    float mrun[4], lrun[4];
    f32x4 o[4];
    #pragma unroll
    for (int j = 0; j < 4; ++j) { mrun[j] = -INFINITY; lrun[j] = 0.f; }
    #pragma unroll
    for (int n = 0; n < 4; ++n) o[n] = (f32x4){0.f, 0.f, 0.f, 0.f};
    const float sc = 0.125f;

    for (int kt = 0; kt < SS / 64; ++kt) {
        __syncthreads();    // prior-iter ksh/vts reads done (covers Q stage at kt=0)
        {   // stage K hi/lo + V transposed
            int r = t >> 2, c0 = (t & 3) * 16;
            size_t srcb = (size_t)(kt * 64 + r) * DH + c0;
            *reinterpret_cast<uint4*>(&ksh[r][c0])     = *reinterpret_cast<const uint4*>(Kh + srcb);
            *reinterpret_cast<uint4*>(&ksh[r][c0 + 8]) = *reinterpret_cast<const uint4*>(Kh + srcb + 8);
            *reinterpret_cast<uint4*>(&ksl[r][c0])     = *reinterpret_cast<const uint4*>(Kl + srcb);
            *reinterpret_cast<uint4*>(&ksl[r][c0 + 8]) = *reinterpret_cast<const uint4*>(Kl + srcb + 8);
            uint4 v0 = *reinterpret_cast<const uint4*>(Vv + srcb);
            uint4 v1 = *reinterpret_cast<const uint4*>(Vv + srcb + 8);
            unsigned short vs16[16] = {
                (unsigned short)(v0.x & 0xffff), (unsigned short)(v0.x >> 16),
                (unsigned short)(v0.y & 0xffff), (unsigned short)(v0.y >> 16),
                (unsigned short)(v0.z & 0xffff), (unsigned short)(v0.z >> 16),
                (unsigned short)(v0.w & 0xffff), (unsigned short)(v0.w >> 16),
                (unsigned short)(v1.x & 0xffff), (unsigned short)(v1.x >> 16),
                (unsigned short)(v1.y & 0xffff), (unsigned short)(v1.y >> 16),
                (unsigned short)(v1.z & 0xffff), (unsigned short)(v1.z >> 16),
                (unsigned short)(v1.w & 0xffff), (unsigned short)(v1.w >> 16)};
            #pragma unroll
            for (int j = 0; j < 16; ++j) vts[c0 + j][r] = vs16[j];
        }
        __syncthreads();

        // ---- S = Q K^T (3-term split), 24 MFMA ----
        f32x4 s[4];
        #pragma unroll
        for (int n = 0; n < 4; ++n) s[n] = (f32x4){0.f, 0.f, 0.f, 0.f};
        #pragma unroll
        for (int ds = 0; ds < 2; ++ds) {
            bf16x8 ah = *reinterpret_cast<const bf16x8*>(&qsh[wid * 16 + fr][ds * 32 + g8]);
            bf16x8 al = *reinterpret_cast<const bf16x8*>(&qsl[wid * 16 + fr][ds * 32 + g8]);
            #pragma unroll
            for (int n = 0; n < 4; ++n) {
                bf16x8 bh = *reinterpret_cast<const bf16x8*>(&ksh[n * 16 + fr][ds * 32 + g8]);
                bf16x8 bl = *reinterpret_cast<const bf16x8*>(&ksl[n * 16 + fr][ds * 32 + g8]);
                s[n] = __builtin_amdgcn_mfma_f32_16x16x32_bf16(ah, bh, s[n], 0, 0, 0);
                s[n] = __builtin_amdgcn_mfma_f32_16x16x32_bf16(ah, bl, s[n], 0, 0, 0);
                s[n] = __builtin_amdgcn_mfma_f32_16x16x32_bf16(al, bh, s[n], 0, 0, 0);
            }
        }

        // ---- online softmax, in-register (rows live in 16-lane groups) ----
        #pragma unroll
        for (int n = 0; n < 4; ++n)
            #pragma unroll
            for (int j = 0; j < 4; ++j) s[n][j] *= sc;

        float rm[4], rs[4], corr[4];
        #pragma unroll
        for (int j = 0; j < 4; ++j)
            rm[j] = fmaxf(fmaxf(s[0][j], s[1][j]), fmaxf(s[2][j], s[3][j]));
        #pragma unroll
        for (int j = 0; j < 4; ++j) {
            #pragma unroll
            for (int off = 1; off < 16; off <<= 1)
                rm[j] = fmaxf(rm[j], __shfl_xor(rm[j], off));
            float nm = fmaxf(mrun[j], rm[j]);
            corr[j] = __expf(mrun[j] - nm);
            mrun[j] = nm;
            rs[j] = 0.f;
        }
        #pragma unroll
        for (int n = 0; n < 4; ++n)
            #pragma unroll
            for (int j = 0; j < 4; ++j) {
                float p = __expf(s[n][j] - mrun[j]);
                s[n][j] = p;
                rs[j] += p;
            }
        #pragma unroll
        for (int j = 0; j < 4; ++j) {
            #pragma unroll
            for (int off = 1; off < 16; off <<= 1)
                rs[j] += __shfl_xor(rs[j], off);
            lrun[j] = lrun[j] * corr[j] + rs[j];
        }
        #pragma unroll
        for (int n = 0; n < 4; ++n)
            #pragma unroll
            for (int j = 0; j < 4; ++j) o[n][j] *= corr[j];

        // P -> LDS (wave-private rows; no barrier needed)
        #pragma unroll
        for (int n = 0; n < 4; ++n)
            #pragma unroll
            for (int j = 0; j < 4; ++j)
                ps[wid * 16 + fg * 4 + j][n * 16 + fr] = s[n][j];

        // ---- O += P V, 8 MFMA ----
        #pragma unroll
        for (int ks = 0; ks < 2; ++ks) {
            const float* prow = &ps[wid * 16 + fr][ks * 32 + g8];
            float4 p0 = *reinterpret_cast<const float4*>(prow);
            float4 p1 = *reinterpret_cast<const float4*>(prow + 4);
            bf16x8 pa;
            pa[0] = (short)f2bf(p0.x); pa[1] = (short)f2bf(p0.y);
            pa[2] = (short)f2bf(p0.z); pa[3] = (short)f2bf(p0.w);
            pa[4] = (short)f2bf(p1.x); pa[5] = (short)f2bf(p1.y);
            pa[6] = (short)f2bf(p1.z); pa[7] = (short)f2bf(p1.w);
            #pragma unroll
            for (int n = 0; n < 4; ++n) {
                bf16x8 bv = *reinterpret_cast<const bf16x8*>(&vts[n * 16 + fr][ks * 32 + g8]);
                o[n] = __builtin_amdgcn_mfma_f32_16x16x32_bf16(pa, bv, o[n], 0, 0, 0);
            }
        }
    }

    float inv[4];
    #pragma unroll
    for (int j = 0; j < 4; ++j) inv[j] = 1.0f / lrun[j];
    #pragma unroll
    for (int n = 0; n < 4; ++n)
        #pragma unroll
        for (int j = 0; j < 4; ++j) {
            int row = qt * 64 + wid * 16 + fg * 4 + j;
            int col = h * DH + n * 16 + fr;
            z[((size_t)b * SS + row) * (size_t)(HH * DH) + col] = f2bf(o[n][j] * inv[j]);
        }
}

// ---------------------------------------------------------------
// outproj: out[m][i] = sum_j wc[i][j] z[m][j]; z bf16, wc split bf16.
// grid 128, block 256, 2-term MFMA.
// ---------------------------------------------------------------
__global__ __launch_bounds__(256) void outproj_kernel(
    const unsigned short* __restrict__ z,
    const unsigned short* __restrict__ wch, const unsigned short* __restrict__ wcl,
    float* __restrict__ out)
{
    const int mt = blockIdx.x, m0 = mt * 64;
    __shared__ unsigned short zs[64][40], wh_[64][40], wl_[64][40];

    const int t = threadIdx.x;
    const int lane = t & 63, wid = t >> 6;
    const int fr = lane & 15, fg = lane >> 4, g8 = fg * 8;

    f32x4 acc[4];
    #pragma unroll
    for (int n = 0; n < 4; ++n) acc[n] = (f32x4){0.f, 0.f, 0.f, 0.f};

    for (int ks = 0; ks < DIN / 32; ++ks) {
        const int k0 = ks * 32;
        {
            int r = t >> 2, c8 = (t & 3) * 8;
            *reinterpret_cast<uint4*>(&zs[r][c8]) =
                *reinterpret_cast<const uint4*>(z + (size_t)(m0 + r) * DIN + k0 + c8);
            size_t wb = (size_t)r * DIN + k0 + c8;
            *reinterpret_cast<uint4*>(&wh_[r][c8]) = *reinterpret_cast<const uint4*>(wch + wb);
            *reinterpret_cast<uint4*>(&wl_[r][c8]) = *reinterpret_cast<const uint4*>(wcl + wb);
        }
        __syncthreads();
        bf16x8 az = *reinterpret_cast<const bf16x8*>(&zs[wid * 16 + fr][g8]);
        #pragma unroll
        for (int n = 0; n < 4; ++n) {
            bf16x8 bh = *reinterpret_cast<const bf16x8*>(&wh_[n * 16 + fr][g8]);
            bf16x8 bl = *reinterpret_cast<const bf16x8*>(&wl_[n * 16 + fr][g8]);
            acc[n] = __builtin_amdgcn_mfma_f32_16x16x32_bf16(az, bh, acc[n], 0, 0, 0);
            acc[n] = __builtin_amdgcn_mfma_f32_16x16x32_bf16(az, bl, acc[n], 0, 0, 0);
        }
        __syncthreads();
    }

    #pragma unroll
    for (int n = 0; n < 4; ++n)
        #pragma unroll
        for (int j = 0; j < 4; ++j) {
            int row = m0 + wid * 16 + fg * 4 + j;
            out[(size_t)row * DH + n * 16 + fr] = acc[n][j];
        }
}

extern "C" void kernel_launch(void* const* d_in, const int* in_sizes, int n_in,
                              void* d_out, int out_size, void* d_ws, size_t ws_size,
                              hipStream_t stream) {
    const float* x  = (const float*)d_in[0];
    const float* wq = (const float*)d_in[1];
    const float* wk = (const float*)d_in[2];
    const float* wv = (const float*)d_in[3];
    const float* wc = (const float*)d_in[4];
    float* out = (float*)d_out;

    // workspace (ushort units), total 82.8 MB:
    const size_t wpl   = (size_t)3 * HH * 64 * DIN;     // 1,769,472
    const size_t plane = (size_t)BB * HH * SS * DH;     // 6,291,456
    unsigned short* whi = (unsigned short*)d_ws;
    unsigned short* wlo = whi + wpl;
    unsigned short* wch = wlo + wpl;
    unsigned short* wcl = wch + (size_t)64 * DIN;
    unsigned short* qh  = wcl + (size_t)64 * DIN;
    unsigned short* ql  = qh + plane;
    unsigned short* kh  = ql + plane;
    unsigned short* kl  = kh + plane;
    unsigned short* vv  = kl + plane;
    unsigned short* zz  = vv + plane;

    prep_w_kernel<<<dim3(12, HH, 3), 256, 0, stream>>>(wq, wk, wv, whi, wlo);
    prep_wc_kernel<<<24, 256, 0, stream>>>(wc, wch, wcl);
    qkv_proj_kernel<<<dim3(40, 128), 256, 0, stream>>>(x, whi, wlo, qh, ql, kh, kl, vv);
    attn_kernel<<<1536, 256, 0, stream>>>(qh, ql, kh, kl, vv, zz);
    outproj_kernel<<<128, 256, 0, stream>>>(zz, wch, wcl, out);
}

// Round 7
// 381.312 us; speedup vs baseline: 7.6042x; 1.1683x over previous
//
#include <hip/hip_runtime.h>
#include <hip/hip_bf16.h>
#include <math.h>

#define BB 4
#define SS 2048
#define DIN 768
#define HH 12
#define DH 64
#define NT (SS / 64)

typedef __attribute__((ext_vector_type(8))) _Float16 f16x8;
typedef __attribute__((ext_vector_type(4))) float f32x4;

// split fp32 -> fp16 hi + fp16 lo (v ~= hi+lo, |lo| <= 2^-11 |v|)
__device__ inline void splith(float v, _Float16& hi, _Float16& lo) {
    hi = (_Float16)v;
    lo = (_Float16)(v - (float)hi);
}

// ---------------------------------------------------------------
// prep_w: W[h][k][n] fp32 -> transposed+split planes whi/wlo[(which,h)][n][k] fp16
// grid (12 ktiles, 12 h, 3 which), block 256
// ---------------------------------------------------------------
__global__ __launch_bounds__(256) void prep_w_kernel(
    const float* __restrict__ wq, const float* __restrict__ wk, const float* __restrict__ wv,
    _Float16* __restrict__ whi, _Float16* __restrict__ wlo)
{
    const int kt = blockIdx.x, h = blockIdx.y, which = blockIdx.z;
    const float* w = (which == 0) ? wq : (which == 1) ? wk : wv;
    w += (size_t)h * (DIN * DH);
    const size_t plane = ((size_t)which * HH + h) * (size_t)(64 * DIN);

    __shared__ float tile[64][65];
    const int t = threadIdx.x;
    {
        int r = t >> 2, n0 = (t & 3) * 16;
        const float* src = w + (size_t)(kt * 64 + r) * DH + n0;
        #pragma unroll
        for (int q = 0; q < 4; ++q) {
            float4 v = *reinterpret_cast<const float4*>(src + q * 4);
            tile[r][n0 + q * 4 + 0] = v.x; tile[r][n0 + q * 4 + 1] = v.y;
            tile[r][n0 + q * 4 + 2] = v.z; tile[r][n0 + q * 4 + 3] = v.w;
        }
    }
    __syncthreads();
    {
        int n = t >> 2, k0 = (t & 3) * 16;
        f16x8 h0, h1, l0, l1;
        #pragma unroll
        for (int j = 0; j < 8; ++j) {
            _Float16 hh, ll;
            splith(tile[k0 + j][n], hh, ll);     h0[j] = hh; l0[j] = ll;
            splith(tile[k0 + 8 + j][n], hh, ll); h1[j] = hh; l1[j] = ll;
        }
        size_t base = plane + (size_t)n * DIN + kt * 64 + k0;
        *reinterpret_cast<f16x8*>(whi + base)     = h0;
        *reinterpret_cast<f16x8*>(whi + base + 8) = h1;
        *reinterpret_cast<f16x8*>(wlo + base)     = l0;
        *reinterpret_cast<f16x8*>(wlo + base + 8) = l1;
    }
}

// prep_wc: wc [64][768] fp32 -> wch/wcl fp16 (same layout). grid 24, block 256.
__global__ __launch_bounds__(256) void prep_wc_kernel(
    const float* __restrict__ wc,
    _Float16* __restrict__ wch, _Float16* __restrict__ wcl)
{
    int idx = (blockIdx.x * 256 + threadIdx.x) * 8;
    float4 a = *reinterpret_cast<const float4*>(wc + idx);
    float4 b = *reinterpret_cast<const float4*>(wc + idx + 4);
    float f[8] = {a.x, a.y, a.z, a.w, b.x, b.y, b.z, b.w};
    f16x8 hv, lv;
    #pragma unroll
    for (int j = 0; j < 8; ++j) {
        _Float16 hh, ll;
        splith(f[j], hh, ll);
        hv[j] = hh; lv[j] = ll;
    }
    *reinterpret_cast<f16x8*>(wch + idx) = hv;
    *reinterpret_cast<f16x8*>(wcl + idx) = lv;
}

// ---------------------------------------------------------------
// qkv_proj: x fp32 [8192][768] x Wsplit -> Q,K hi+lo fp16 [b][h][s][64],
// V fp16 TRANSPOSED [b][h][d][s].  3-term split MFMA
// (xh*wh + xh*wl + xl*wh) — restores round-4 numerics (x-lo kept!).
// grid (40, 128): bx%8 pins (which,h) weight plane to one XCD; bx>=36 idle.
// ---------------------------------------------------------------
__global__ __launch_bounds__(256) void qkv_proj_kernel(
    const float* __restrict__ x,
    const _Float16* __restrict__ whi, const _Float16* __restrict__ wlo,
    _Float16* __restrict__ qh, _Float16* __restrict__ ql,
    _Float16* __restrict__ kh, _Float16* __restrict__ kl,
    _Float16* __restrict__ vt)
{
    const int hw = blockIdx.x;
    if (hw >= 36) return;
    const int which = hw / HH, h = hw % HH;
    const int mt = blockIdx.y, m0 = mt * 64;
    const size_t wplane = ((size_t)which * HH + h) * (size_t)(64 * DIN);

    __shared__ _Float16 xsh[64][40], xsl[64][40], wsh[64][40], wsl[64][40];
    __shared__ _Float16 vtile[64][72];   // only used by which==2: [d][s_local]

    const int t = threadIdx.x;
    const int lane = t & 63, wid = t >> 6;
    const int fr = lane & 15, fg = lane >> 4, g8 = fg * 8;

    f32x4 acc[4];
    #pragma unroll
    for (int n = 0; n < 4; ++n) acc[n] = (f32x4){0.f, 0.f, 0.f, 0.f};

    for (int ks = 0; ks < DIN / 32; ++ks) {
        const int k0 = ks * 32;
        {
            int r = t >> 2, c8 = (t & 3) * 8;
            const float* xp = x + (size_t)(m0 + r) * DIN + k0 + c8;
            float4 a = *reinterpret_cast<const float4*>(xp);
            float4 b = *reinterpret_cast<const float4*>(xp + 4);
            float f[8] = {a.x, a.y, a.z, a.w, b.x, b.y, b.z, b.w};
            f16x8 xh, xl;
            #pragma unroll
            for (int j = 0; j < 8; ++j) {
                _Float16 hh, ll;
                splith(f[j], hh, ll);
                xh[j] = hh; xl[j] = ll;
            }
            *reinterpret_cast<f16x8*>(&xsh[r][c8]) = xh;
            *reinterpret_cast<f16x8*>(&xsl[r][c8]) = xl;
            size_t wb = wplane + (size_t)r * DIN + k0 + c8;
            *reinterpret_cast<f16x8*>(&wsh[r][c8]) = *reinterpret_cast<const f16x8*>(whi + wb);
            *reinterpret_cast<f16x8*>(&wsl[r][c8]) = *reinterpret_cast<const f16x8*>(wlo + wb);
        }
        __syncthreads();
        f16x8 ah = *reinterpret_cast<const f16x8*>(&xsh[wid * 16 + fr][g8]);
        f16x8 al = *reinterpret_cast<const f16x8*>(&xsl[wid * 16 + fr][g8]);
        #pragma unroll
        for (int n = 0; n < 4; ++n) {
            f16x8 bh = *reinterpret_cast<const f16x8*>(&wsh[n * 16 + fr][g8]);
            f16x8 bl = *reinterpret_cast<const f16x8*>(&wsl[n * 16 + fr][g8]);
            acc[n] = __builtin_amdgcn_mfma_f32_16x16x32_f16(ah, bh, acc[n], 0, 0, 0);
            acc[n] = __builtin_amdgcn_mfma_f32_16x16x32_f16(ah, bl, acc[n], 0, 0, 0);
            acc[n] = __builtin_amdgcn_mfma_f32_16x16x32_f16(al, bh, acc[n], 0, 0, 0);
        }
        __syncthreads();
    }

    if (which == 2) {
        // acc[n][j] = V[s_local = wid*16+fg*4+j][d = n*16+fr]
        // store vtile[d][s_local] so the row-store below writes vt[b][h][d][s]
        #pragma unroll
        for (int n = 0; n < 4; ++n)
            #pragma unroll
            for (int j = 0; j < 4; ++j)
                vtile[n * 16 + fr][wid * 16 + fg * 4 + j] = (_Float16)acc[n][j];
        __syncthreads();
        int r = t >> 2, c0 = (t & 3) * 16;     // r = d, c0 = s_local
        int b0 = m0 >> 11, s0 = m0 & 2047;
        size_t base = (((size_t)b0 * HH + h) * DH + r) * SS + s0 + c0;
        *reinterpret_cast<uint4*>(vt + base)     = *reinterpret_cast<uint4*>(&vtile[r][c0]);
        *reinterpret_cast<uint4*>(vt + base + 8) = *reinterpret_cast<uint4*>(&vtile[r][c0 + 8]);
    } else {
        #pragma unroll
        for (int n = 0; n < 4; ++n)
            #pragma unroll
            for (int j = 0; j < 4; ++j) {
                int row = wid * 16 + fg * 4 + j;
                int m = m0 + row, bb = m >> 11, ss = m & 2047;
                size_t idx = (((size_t)bb * HH + h) * SS + ss) * DH + n * 16 + fr;
                _Float16 hi, lo;
                splith(acc[n][j], hi, lo);
                if (which == 0) { qh[idx] = hi; ql[idx] = lo; }
                else            { kh[idx] = hi; kl[idx] = lo; }
            }
    }
}

// ---------------------------------------------------------------
// attn: flash MFMA fp16. 64 q-rows/block, 4 waves x 16 rows, KV tiles of 64.
// Q hi+lo loaded DIRECT global->registers (no Q LDS, no union).
// S = qh*kh + qh*kl + ql*kh (24 MFMA, near-exact scores);
// softmax in-register; P via standalone fp32 LDS (wave-private);
// V^T staged with vector writes. Reg-prefetch of next K/V tile.
// grid 1536, XCD-chunk swizzled. z out [b][s][768] fp16.
// ---------------------------------------------------------------
__global__ __launch_bounds__(256) void attn_kernel(
    const _Float16* __restrict__ qhp, const _Float16* __restrict__ qlp,
    const _Float16* __restrict__ khp, const _Float16* __restrict__ klp,
    const _Float16* __restrict__ vtp,
    _Float16* __restrict__ z)
{
    const int flat = blockIdx.x;
    const int remap = (flat & 7) * 192 + (flat >> 3);   // bijective, 1536 = 8*192
    const int qt = remap & 31;
    const int h  = (remap >> 5) % HH;
    const int b  = remap / (32 * HH);

    const size_t headbase = ((size_t)b * HH + h) * (size_t)(SS * DH);
    const _Float16* Qh = qhp + headbase;
    const _Float16* Ql = qlp + headbase;
    const _Float16* Kh = khp + headbase;
    const _Float16* Kl = klp + headbase;
    const _Float16* Vt = vtp + headbase;   // [d][s]

    __shared__ _Float16 ksh[64][72], ksl[64][72], vts[64][72];
    __shared__ float psm[64][68];          // P fp32, standalone (no union!)

    const int t = threadIdx.x;
    const int lane = t & 63, wid = t >> 6;
    const int fr = lane & 15, fg = lane >> 4, g8 = fg * 8;
    const int r4 = t >> 2, c16 = (t & 3) * 16;

    // Q fragments: direct global -> regs, once per block
    const size_t qrow = (size_t)(qt * 64 + wid * 16 + fr) * DH;
    f16x8 aqh0 = *reinterpret_cast<const f16x8*>(Qh + qrow + g8);
    f16x8 aqh1 = *reinterpret_cast<const f16x8*>(Qh + qrow + 32 + g8);
    f16x8 aql0 = *reinterpret_cast<const f16x8*>(Ql + qrow + g8);
    f16x8 aql1 = *reinterpret_cast<const f16x8*>(Ql + qrow + 32 + g8);

    uint4 rk0, rk1, rl0, rl1, rv0, rv1;
    auto prefetch = [&](int kt) {
        size_t sk = (size_t)(kt * 64 + r4) * DH + c16;
        rk0 = *reinterpret_cast<const uint4*>(Kh + sk);
        rk1 = *reinterpret_cast<const uint4*>(Kh + sk + 8);
        rl0 = *reinterpret_cast<const uint4*>(Kl + sk);
        rl1 = *reinterpret_cast<const uint4*>(Kl + sk + 8);
        size_t sv = (size_t)r4 * SS + kt * 64 + c16;
        rv0 = *reinterpret_cast<const uint4*>(Vt + sv);
        rv1 = *reinterpret_cast<const uint4*>(Vt + sv + 8);
    };
    prefetch(0);

    float mrun[4], lrun[4];
    f32x4 o[4];
    #pragma unroll
    for (int j = 0; j < 4; ++j) { mrun[j] = -INFINITY; lrun[j] = 0.f; }
    #pragma unroll
    for (int n = 0; n < 4; ++n) o[n] = (f32x4){0.f, 0.f, 0.f, 0.f};
    const float sc = 0.125f;

    for (int kt = 0; kt < NT; ++kt) {
        __syncthreads();   // prior compute done reading ksh/ksl/vts/psm
        *reinterpret_cast<uint4*>(&ksh[r4][c16])     = rk0;
        *reinterpret_cast<uint4*>(&ksh[r4][c16 + 8]) = rk1;
        *reinterpret_cast<uint4*>(&ksl[r4][c16])     = rl0;
        *reinterpret_cast<uint4*>(&ksl[r4][c16 + 8]) = rl1;
        *reinterpret_cast<uint4*>(&vts[r4][c16])     = rv0;
        *reinterpret_cast<uint4*>(&vts[r4][c16 + 8]) = rv1;
        if (kt + 1 < NT) prefetch(kt + 1);   // overlaps with compute below
        __syncthreads();   // LDS tile ready

        // ---- S = Q K^T (qh*kh + qh*kl + ql*kh), 24 MFMA ----
        f32x4 s[4];
        #pragma unroll
        for (int n = 0; n < 4; ++n) s[n] = (f32x4){0.f, 0.f, 0.f, 0.f};
        #pragma unroll
        for (int n = 0; n < 4; ++n) {
            f16x8 bh0 = *reinterpret_cast<const f16x8*>(&ksh[n * 16 + fr][g8]);
            f16x8 bl0 = *reinterpret_cast<const f16x8*>(&ksl[n * 16 + fr][g8]);
            s[n] = __builtin_amdgcn_mfma_f32_16x16x32_f16(aqh0, bh0, s[n], 0, 0, 0);
            s[n] = __builtin_amdgcn_mfma_f32_16x16x32_f16(aqh0, bl0, s[n], 0, 0, 0);
            s[n] = __builtin_amdgcn_mfma_f32_16x16x32_f16(aql0, bh0, s[n], 0, 0, 0);
            f16x8 bh1 = *reinterpret_cast<const f16x8*>(&ksh[n * 16 + fr][32 + g8]);
            f16x8 bl1 = *reinterpret_cast<const f16x8*>(&ksl[n * 16 + fr][32 + g8]);
            s[n] = __builtin_amdgcn_mfma_f32_16x16x32_f16(aqh1, bh1, s[n], 0, 0, 0);
            s[n] = __builtin_amdgcn_mfma_f32_16x16x32_f16(aqh1, bl1, s[n], 0, 0, 0);
            s[n] = __builtin_amdgcn_mfma_f32_16x16x32_f16(aql1, bh1, s[n], 0, 0, 0);
        }

        // ---- online softmax in-register ----
        #pragma unroll
        for (int n = 0; n < 4; ++n)
            #pragma unroll
            for (int j = 0; j < 4; ++j) s[n][j] *= sc;

        float rm[4], rs[4], corr[4];
        #pragma unroll
        for (int j = 0; j < 4; ++j)
            rm[j] = fmaxf(fmaxf(s[0][j], s[1][j]), fmaxf(s[2][j], s[3][j]));
        #pragma unroll
        for (int j = 0; j < 4; ++j) {
            #pragma unroll
            for (int off = 1; off < 16; off <<= 1)
                rm[j] = fmaxf(rm[j], __shfl_xor(rm[j], off));
            float nm = fmaxf(mrun[j], rm[j]);
            corr[j] = __expf(mrun[j] - nm);
            mrun[j] = nm;
            rs[j] = 0.f;
        }
        #pragma unroll
        for (int n = 0; n < 4; ++n)
            #pragma unroll
            for (int j = 0; j < 4; ++j) {
                float p = __expf(s[n][j] - mrun[j]);
                s[n][j] = p;
                rs[j] += p;
            }
        #pragma unroll
        for (int j = 0; j < 4; ++j) {
            #pragma unroll
            for (int off = 1; off < 16; off <<= 1)
                rs[j] += __shfl_xor(rs[j], off);
            lrun[j] = lrun[j] * corr[j] + rs[j];
        }
        #pragma unroll
        for (int n = 0; n < 4; ++n)
            #pragma unroll
            for (int j = 0; j < 4; ++j) o[n][j] *= corr[j];

        // P -> LDS (wave-private rows)
        #pragma unroll
        for (int n = 0; n < 4; ++n)
            #pragma unroll
            for (int j = 0; j < 4; ++j)
                psm[wid * 16 + fg * 4 + j][n * 16 + fr] = s[n][j];

        // ---- O += P V, 8 MFMA ----
        #pragma unroll
        for (int ks = 0; ks < 2; ++ks) {
            const float* prow = &psm[wid * 16 + fr][ks * 32 + g8];
            float4 p0 = *reinterpret_cast<const float4*>(prow);
            float4 p1 = *reinterpret_cast<const float4*>(prow + 4);
            f16x8 pa;
            pa[0] = (_Float16)p0.x; pa[1] = (_Float16)p0.y;
            pa[2] = (_Float16)p0.z; pa[3] = (_Float16)p0.w;
            pa[4] = (_Float16)p1.x; pa[5] = (_Float16)p1.y;
            pa[6] = (_Float16)p1.z; pa[7] = (_Float16)p1.w;
            #pragma unroll
            for (int n = 0; n < 4; ++n) {
                f16x8 bv = *reinterpret_cast<const f16x8*>(&vts[n * 16 + fr][ks * 32 + g8]);
                o[n] = __builtin_amdgcn_mfma_f32_16x16x32_f16(pa, bv, o[n], 0, 0, 0);
            }
        }
    }

    float inv[4];
    #pragma unroll
    for (int j = 0; j < 4; ++j) inv[j] = 1.0f / lrun[j];
    #pragma unroll
    for (int n = 0; n < 4; ++n)
        #pragma unroll
        for (int j = 0; j < 4; ++j) {
            int row = qt * 64 + wid * 16 + fg * 4 + j;
            int col = h * DH + n * 16 + fr;
            z[((size_t)b * SS + row) * (size_t)(HH * DH) + col] = (_Float16)(o[n][j] * inv[j]);
        }
}

// ---------------------------------------------------------------
// outproj: out[m][i] = sum_j wc[i][j] z[m][j]; z fp16, wc split fp16 2-term.
// grid 128, block 256.
// ---------------------------------------------------------------
__global__ __launch_bounds__(256) void outproj_kernel(
    const _Float16* __restrict__ z,
    const _Float16* __restrict__ wch, const _Float16* __restrict__ wcl,
    float* __restrict__ out)
{
    const int mt = blockIdx.x, m0 = mt * 64;
    __shared__ _Float16 zs[64][40], wh_[64][40], wl_[64][40];

    const int t = threadIdx.x;
    const int lane = t & 63, wid = t >> 6;
    const int fr = lane & 15, fg = lane >> 4, g8 = fg * 8;

    f32x4 acc[4];
    #pragma unroll
    for (int n = 0; n < 4; ++n) acc[n] = (f32x4){0.f, 0.f, 0.f, 0.f};

    for (int ks = 0; ks < DIN / 32; ++ks) {
        const int k0 = ks * 32;
        {
            int r = t >> 2, c8 = (t & 3) * 8;
            *reinterpret_cast<f16x8*>(&zs[r][c8]) =
                *reinterpret_cast<const f16x8*>(z + (size_t)(m0 + r) * DIN + k0 + c8);
            size_t wb = (size_t)r * DIN + k0 + c8;
            *reinterpret_cast<f16x8*>(&wh_[r][c8]) = *reinterpret_cast<const f16x8*>(wch + wb);
            *reinterpret_cast<f16x8*>(&wl_[r][c8]) = *reinterpret_cast<const f16x8*>(wcl + wb);
        }
        __syncthreads();
        f16x8 az = *reinterpret_cast<const f16x8*>(&zs[wid * 16 + fr][g8]);
        #pragma unroll
        for (int n = 0; n < 4; ++n) {
            f16x8 bh = *reinterpret_cast<const f16x8*>(&wh_[n * 16 + fr][g8]);
            f16x8 bl = *reinterpret_cast<const f16x8*>(&wl_[n * 16 + fr][g8]);
            acc[n] = __builtin_amdgcn_mfma_f32_16x16x32_f16(az, bh, acc[n], 0, 0, 0);
            acc[n] = __builtin_amdgcn_mfma_f32_16x16x32_f16(az, bl, acc[n], 0, 0, 0);
        }
        __syncthreads();
    }

    #pragma unroll
    for (int n = 0; n < 4; ++n)
        #pragma unroll
        for (int j = 0; j < 4; ++j) {
            int row = m0 + wid * 16 + fg * 4 + j;
            out[(size_t)row * DH + n * 16 + fr] = acc[n][j];
        }
}

extern "C" void kernel_launch(void* const* d_in, const int* in_sizes, int n_in,
                              void* d_out, int out_size, void* d_ws, size_t ws_size,
                              hipStream_t stream) {
    const float* x  = (const float*)d_in[0];
    const float* wq = (const float*)d_in[1];
    const float* wk = (const float*)d_in[2];
    const float* wv = (const float*)d_in[3];
    const float* wc = (const float*)d_in[4];
    float* out = (float*)d_out;

    // workspace (_Float16 units), total ~82.8 MB (same as passing round 4):
    const size_t wpl   = (size_t)3 * HH * 64 * DIN;     // 1,769,472
    const size_t plane = (size_t)BB * HH * SS * DH;     // 6,291,456
    _Float16* whi = (_Float16*)d_ws;
    _Float16* wlo = whi + wpl;
    _Float16* wch = wlo + wpl;
    _Float16* wcl = wch + (size_t)64 * DIN;
    _Float16* qh  = wcl + (size_t)64 * DIN;
    _Float16* ql  = qh + plane;
    _Float16* kh  = ql + plane;
    _Float16* kl  = kh + plane;
    _Float16* vt  = kl + plane;   // [b][h][d][s]
    _Float16* zz  = vt + plane;

    prep_w_kernel<<<dim3(12, HH, 3), 256, 0, stream>>>(wq, wk, wv, whi, wlo);
    prep_wc_kernel<<<24, 256, 0, stream>>>(wc, wch, wcl);
    qkv_proj_kernel<<<dim3(40, 128), 256, 0, stream>>>(x, whi, wlo, qh, ql, kh, kl, vt);
    attn_kernel<<<1536, 256, 0, stream>>>(qh, ql, kh, kl, vt, zz);
    outproj_kernel<<<128, 256, 0, stream>>>(zz, wch, wcl, out);
}

// Round 8
// 273.472 us; speedup vs baseline: 10.6027x; 1.3943x over previous
//
#include <hip/hip_runtime.h>
#include <hip/hip_bf16.h>
#include <math.h>

#define BB 4
#define SS 2048
#define DIN 768
#define HH 12
#define DH 64
#define NT (SS / 64)

typedef __attribute__((ext_vector_type(8))) _Float16 f16x8;
typedef __attribute__((ext_vector_type(4))) _Float16 f16x4;
typedef __attribute__((ext_vector_type(2))) _Float16 f16x2;
typedef __attribute__((ext_vector_type(4))) float f32x4;
typedef __attribute__((ext_vector_type(16))) float f32x16;
typedef __attribute__((ext_vector_type(4))) unsigned u32x4;

// split fp32 -> fp16 hi + fp16 lo (v ~= hi+lo, |lo| <= 2^-11 |v|)
__device__ inline void splith(float v, _Float16& hi, _Float16& lo) {
    hi = (_Float16)v;
    lo = (_Float16)(v - (float)hi);
}
__device__ inline unsigned packh2(float a, float b) {
    f16x2 h; h[0] = (_Float16)a; h[1] = (_Float16)b;
    return __builtin_bit_cast(unsigned, h);
}
// 16B fp16 fragment via two 8B LDS reads (stride-68 rows are only 8B-aligned)
__device__ inline f16x8 ldb64x2(const _Float16* p) {
    const uint2* q = reinterpret_cast<const uint2*>(p);
    uint2 a = q[0], b = q[1];
    u32x4 u = {a.x, a.y, b.x, b.y};
    return __builtin_bit_cast(f16x8, u);
}
__device__ inline void stb64x2(_Float16* p, uint4 v) {
    uint2* q = reinterpret_cast<uint2*>(p);
    q[0] = make_uint2(v.x, v.y);
    q[1] = make_uint2(v.z, v.w);
}
__device__ inline f32x16 zero16() {
    f32x16 v;
    #pragma unroll
    for (int i = 0; i < 16; ++i) v[i] = 0.f;
    return v;
}

// ---------------------------------------------------------------
// prep_w: W[h][k][n] fp32 -> transposed+split planes whi/wlo[(which,h)][n][k] fp16
// grid (12 ktiles, 12 h, 3 which), block 256
// ---------------------------------------------------------------
__global__ __launch_bounds__(256) void prep_w_kernel(
    const float* __restrict__ wq, const float* __restrict__ wk, const float* __restrict__ wv,
    _Float16* __restrict__ whi, _Float16* __restrict__ wlo)
{
    const int kt = blockIdx.x, h = blockIdx.y, which = blockIdx.z;
    const float* w = (which == 0) ? wq : (which == 1) ? wk : wv;
    w += (size_t)h * (DIN * DH);
    const size_t plane = ((size_t)which * HH + h) * (size_t)(64 * DIN);

    __shared__ float tile[64][65];
    const int t = threadIdx.x;
    {
        int r = t >> 2, n0 = (t & 3) * 16;
        const float* src = w + (size_t)(kt * 64 + r) * DH + n0;
        #pragma unroll
        for (int q = 0; q < 4; ++q) {
            float4 v = *reinterpret_cast<const float4*>(src + q * 4);
            tile[r][n0 + q * 4 + 0] = v.x; tile[r][n0 + q * 4 + 1] = v.y;
            tile[r][n0 + q * 4 + 2] = v.z; tile[r][n0 + q * 4 + 3] = v.w;
        }
    }
    __syncthreads();
    {
        int n = t >> 2, k0 = (t & 3) * 16;
        f16x8 h0, h1, l0, l1;
        #pragma unroll
        for (int j = 0; j < 8; ++j) {
            _Float16 hh, ll;
            splith(tile[k0 + j][n], hh, ll);     h0[j] = hh; l0[j] = ll;
            splith(tile[k0 + 8 + j][n], hh, ll); h1[j] = hh; l1[j] = ll;
        }
        size_t base = plane + (size_t)n * DIN + kt * 64 + k0;
        *reinterpret_cast<f16x8*>(whi + base)     = h0;
        *reinterpret_cast<f16x8*>(whi + base + 8) = h1;
        *reinterpret_cast<f16x8*>(wlo + base)     = l0;
        *reinterpret_cast<f16x8*>(wlo + base + 8) = l1;
    }
}

// prep_wc: wc [64][768] fp32 -> wch/wcl fp16 (same layout). grid 24, block 256.
__global__ __launch_bounds__(256) void prep_wc_kernel(
    const float* __restrict__ wc,
    _Float16* __restrict__ wch, _Float16* __restrict__ wcl)
{
    int idx = (blockIdx.x * 256 + threadIdx.x) * 8;
    float4 a = *reinterpret_cast<const float4*>(wc + idx);
    float4 b = *reinterpret_cast<const float4*>(wc + idx + 4);
    float f[8] = {a.x, a.y, a.z, a.w, b.x, b.y, b.z, b.w};
    f16x8 hv, lv;
    #pragma unroll
    for (int j = 0; j < 8; ++j) {
        _Float16 hh, ll;
        splith(f[j], hh, ll);
        hv[j] = hh; lv[j] = ll;
    }
    *reinterpret_cast<f16x8*>(wch + idx) = hv;
    *reinterpret_cast<f16x8*>(wcl + idx) = lv;
}

// ---------------------------------------------------------------
// qkv_proj: x fp32 [8192][768] x Wsplit -> Q,K hi+lo fp16 [b][h][s][64],
// V fp16 TRANSPOSED [b][h][d][s].  3-term split MFMA.
// Q is pre-scaled by 0.125 (1/sqrt(64)) — exact under hi/lo split.
// grid (40, 128): bx%8 pins (which,h) weight plane to one XCD; bx>=36 idle.
// ---------------------------------------------------------------
__global__ __launch_bounds__(256) void qkv_proj_kernel(
    const float* __restrict__ x,
    const _Float16* __restrict__ whi, const _Float16* __restrict__ wlo,
    _Float16* __restrict__ qh, _Float16* __restrict__ ql,
    _Float16* __restrict__ kh, _Float16* __restrict__ kl,
    _Float16* __restrict__ vt)
{
    const int hw = blockIdx.x;
    if (hw >= 36) return;
    const int which = hw / HH, h = hw % HH;
    const int mt = blockIdx.y, m0 = mt * 64;
    const size_t wplane = ((size_t)which * HH + h) * (size_t)(64 * DIN);

    __shared__ _Float16 xsh[64][40], xsl[64][40], wsh[64][40], wsl[64][40];
    __shared__ _Float16 vtile[64][72];   // only used by which==2: [d][s_local]

    const int t = threadIdx.x;
    const int lane = t & 63, wid = t >> 6;
    const int fr = lane & 15, fg = lane >> 4, g8 = fg * 8;

    f32x4 acc[4];
    #pragma unroll
    for (int n = 0; n < 4; ++n) acc[n] = (f32x4){0.f, 0.f, 0.f, 0.f};

    for (int ks = 0; ks < DIN / 32; ++ks) {
        const int k0 = ks * 32;
        {
            int r = t >> 2, c8 = (t & 3) * 8;
            const float* xp = x + (size_t)(m0 + r) * DIN + k0 + c8;
            float4 a = *reinterpret_cast<const float4*>(xp);
            float4 b = *reinterpret_cast<const float4*>(xp + 4);
            float f[8] = {a.x, a.y, a.z, a.w, b.x, b.y, b.z, b.w};
            f16x8 xh, xl;
            #pragma unroll
            for (int j = 0; j < 8; ++j) {
                _Float16 hh, ll;
                splith(f[j], hh, ll);
                xh[j] = hh; xl[j] = ll;
            }
            *reinterpret_cast<f16x8*>(&xsh[r][c8]) = xh;
            *reinterpret_cast<f16x8*>(&xsl[r][c8]) = xl;
            size_t wb = wplane + (size_t)r * DIN + k0 + c8;
            *reinterpret_cast<f16x8*>(&wsh[r][c8]) = *reinterpret_cast<const f16x8*>(whi + wb);
            *reinterpret_cast<f16x8*>(&wsl[r][c8]) = *reinterpret_cast<const f16x8*>(wlo + wb);
        }
        __syncthreads();
        f16x8 ah = *reinterpret_cast<const f16x8*>(&xsh[wid * 16 + fr][g8]);
        f16x8 al = *reinterpret_cast<const f16x8*>(&xsl[wid * 16 + fr][g8]);
        #pragma unroll
        for (int n = 0; n < 4; ++n) {
            f16x8 bh = *reinterpret_cast<const f16x8*>(&wsh[n * 16 + fr][g8]);
            f16x8 bl = *reinterpret_cast<const f16x8*>(&wsl[n * 16 + fr][g8]);
            acc[n] = __builtin_amdgcn_mfma_f32_16x16x32_f16(ah, bh, acc[n], 0, 0, 0);
            acc[n] = __builtin_amdgcn_mfma_f32_16x16x32_f16(ah, bl, acc[n], 0, 0, 0);
            acc[n] = __builtin_amdgcn_mfma_f32_16x16x32_f16(al, bh, acc[n], 0, 0, 0);
        }
        __syncthreads();
    }

    if (which == 2) {
        // acc[n][j] = V[s_local = wid*16+fg*4+j][d = n*16+fr]
        #pragma unroll
        for (int n = 0; n < 4; ++n)
            #pragma unroll
            for (int j = 0; j < 4; ++j)
                vtile[n * 16 + fr][wid * 16 + fg * 4 + j] = (_Float16)acc[n][j];
        __syncthreads();
        int r = t >> 2, c0 = (t & 3) * 16;     // r = d, c0 = s_local
        int b0 = m0 >> 11, s0 = m0 & 2047;
        size_t base = (((size_t)b0 * HH + h) * DH + r) * SS + s0 + c0;
        *reinterpret_cast<uint4*>(vt + base)     = *reinterpret_cast<uint4*>(&vtile[r][c0]);
        *reinterpret_cast<uint4*>(vt + base + 8) = *reinterpret_cast<uint4*>(&vtile[r][c0 + 8]);
    } else {
        #pragma unroll
        for (int n = 0; n < 4; ++n)
            #pragma unroll
            for (int j = 0; j < 4; ++j) {
                int row = wid * 16 + fg * 4 + j;
                int m = m0 + row, bb = m >> 11, ss = m & 2047;
                size_t idx = (((size_t)bb * HH + h) * SS + ss) * DH + n * 16 + fr;
                float val = acc[n][j];
                if (which == 0) val *= 0.125f;   // fold 1/sqrt(D) into Q (exact pow2)
                _Float16 hi, lo;
                splith(val, hi, lo);
                if (which == 0) { qh[idx] = hi; ql[idx] = lo; }
                else            { kh[idx] = hi; kl[idx] = lo; }
            }
    }
}

// ---------------------------------------------------------------
// attn v2: 32x32x16 MFMA, swapped QK^T (S^T = K.Q^T), O^T = V^T.P.
// Block = 128 q-rows, 4 waves x 32 q-cols, kv tiles of 64.
// Softmax fully lane-local (lane owns one q-row; pair via shfl_xor 32).
// P stays in registers: packh2 + v_permlane32_swap -> PV B-frags.
// grid 768 (= 3 blocks/CU), XCD-chunk swizzled.
// ---------------------------------------------------------------
__global__ __launch_bounds__(256, 3) void attn_kernel(
    const _Float16* __restrict__ qhp, const _Float16* __restrict__ qlp,
    const _Float16* __restrict__ khp, const _Float16* __restrict__ klp,
    const _Float16* __restrict__ vtp,
    _Float16* __restrict__ z)
{
    const int flat = blockIdx.x;
    const int remap = (flat & 7) * 96 + (flat >> 3);   // bijective, 768 = 8*96
    const int qt = remap & 15;                          // 16 tiles of 128 q-rows
    const int h  = (remap >> 4) % HH;
    const int b  = remap / (16 * HH);

    const size_t headbase = ((size_t)b * HH + h) * (size_t)(SS * DH);
    const _Float16* Qh = qhp + headbase;
    const _Float16* Ql = qlp + headbase;
    const _Float16* Kh = khp + headbase;
    const _Float16* Kl = klp + headbase;
    const _Float16* Vt = vtp + headbase;   // [d][s]

    __shared__ _Float16 ksh[64][68], ksl[64][68], vts[64][68];

    const int t = threadIdx.x;
    const int lane = t & 63, w = t >> 6;
    const int qcol = lane & 31, hi = lane >> 5;
    const int r4 = t >> 2, c16 = (t & 3) * 16;

    // Q B-frags (B[k=d][n=q]): lane holds Q[q = qt*128 + w*32 + qcol][d = hi*8 + j + 16ks]
    const size_t qbase = (size_t)(qt * 128 + w * 32 + qcol) * DH + hi * 8;
    f16x8 bqh[4], bql[4];
    #pragma unroll
    for (int ks = 0; ks < 4; ++ks) {
        bqh[ks] = *reinterpret_cast<const f16x8*>(Qh + qbase + 16 * ks);
        bql[ks] = *reinterpret_cast<const f16x8*>(Ql + qbase + 16 * ks);
    }

    uint4 rk0, rk1, rl0, rl1, rv0, rv1;
    auto prefetch = [&](int kt) {
        size_t sk = (size_t)(kt * 64 + r4) * DH + c16;
        rk0 = *reinterpret_cast<const uint4*>(Kh + sk);
        rk1 = *reinterpret_cast<const uint4*>(Kh + sk + 8);
        rl0 = *reinterpret_cast<const uint4*>(Kl + sk);
        rl1 = *reinterpret_cast<const uint4*>(Kl + sk + 8);
        size_t sv = (size_t)r4 * SS + kt * 64 + c16;
        rv0 = *reinterpret_cast<const uint4*>(Vt + sv);
        rv1 = *reinterpret_cast<const uint4*>(Vt + sv + 8);
    };
    prefetch(0);

    float mrun = -INFINITY, lrun = 0.f;    // per-lane: lane owns q-row qcol
    f32x16 oc0 = zero16(), oc1 = zero16(); // O^T: d 0-31 / d 32-63, col = q

    for (int kt = 0; kt < NT; ++kt) {
        __syncthreads();   // prior compute done reading ksh/ksl/vts
        stb64x2(&ksh[r4][c16],     rk0);
        stb64x2(&ksh[r4][c16 + 8], rk1);
        stb64x2(&ksl[r4][c16],     rl0);
        stb64x2(&ksl[r4][c16 + 8], rl1);
        stb64x2(&vts[r4][c16],     rv0);
        stb64x2(&vts[r4][c16 + 8], rv1);
        if (kt + 1 < NT) prefetch(kt + 1);
        __syncthreads();   // tile ready

        // ---- S^T = K.Q^T  (kh*qh + kh*ql + kl*qh), 24 MFMA 32x32x16 ----
        f32x16 c0 = zero16(), c1 = zero16();   // kv 0-31 / kv 32-63, col = q
        #pragma unroll
        for (int ks = 0; ks < 4; ++ks) {
            const int doff = hi * 8 + 16 * ks;
            f16x8 a0h = ldb64x2(&ksh[qcol][doff]);
            f16x8 a0l = ldb64x2(&ksl[qcol][doff]);
            c0 = __builtin_amdgcn_mfma_f32_32x32x16_f16(a0h, bqh[ks], c0, 0, 0, 0);
            c0 = __builtin_amdgcn_mfma_f32_32x32x16_f16(a0h, bql[ks], c0, 0, 0, 0);
            c0 = __builtin_amdgcn_mfma_f32_32x32x16_f16(a0l, bqh[ks], c0, 0, 0, 0);
            f16x8 a1h = ldb64x2(&ksh[qcol + 32][doff]);
            f16x8 a1l = ldb64x2(&ksl[qcol + 32][doff]);
            c1 = __builtin_amdgcn_mfma_f32_32x32x16_f16(a1h, bqh[ks], c1, 0, 0, 0);
            c1 = __builtin_amdgcn_mfma_f32_32x32x16_f16(a1h, bql[ks], c1, 0, 0, 0);
            c1 = __builtin_amdgcn_mfma_f32_32x32x16_f16(a1l, bqh[ks], c1, 0, 0, 0);
        }

        // ---- softmax: lane-local over its q-row (scores pre-scaled) ----
        float mx = c0[0];
        #pragma unroll
        for (int i = 1; i < 16; ++i) mx = fmaxf(mx, c0[i]);
        #pragma unroll
        for (int i = 0; i < 16; ++i) mx = fmaxf(mx, c1[i]);
        mx = fmaxf(mx, __shfl_xor(mx, 32));
        float nm = fmaxf(mrun, mx);
        float corr = __expf(mrun - nm);
        float sum = 0.f;
        #pragma unroll
        for (int i = 0; i < 16; ++i) { float p = __expf(c0[i] - nm); c0[i] = p; sum += p; }
        #pragma unroll
        for (int i = 0; i < 16; ++i) { float p = __expf(c1[i] - nm); c1[i] = p; sum += p; }
        sum += __shfl_xor(sum, 32);
        lrun = lrun * corr + sum;
        mrun = nm;
        #pragma unroll
        for (int i = 0; i < 16; ++i) { oc0[i] *= corr; oc1[i] *= corr; }

        // ---- P -> PV B-frags in registers (packh2 + permlane32_swap) ----
        auto mk = [](float s0, float s1, float s2, float s3,
                     float s4, float s5, float s6, float s7) -> f16x8 {
            unsigned a0 = packh2(s0, s1), a1 = packh2(s2, s3);
            unsigned b0 = packh2(s4, s5), b1 = packh2(s6, s7);
            asm volatile("v_permlane32_swap_b32 %0, %1" : "+v"(a0), "+v"(b0));
            asm volatile("v_permlane32_swap_b32 %0, %1" : "+v"(a1), "+v"(b1));
            u32x4 u = {a0, a1, b0, b1};
            return __builtin_bit_cast(f16x8, u);
        };
        f16x8 bp0 = mk(c0[0], c0[1], c0[2],  c0[3],  c0[4],  c0[5],  c0[6],  c0[7]);
        f16x8 bp1 = mk(c0[8], c0[9], c0[10], c0[11], c0[12], c0[13], c0[14], c0[15]);
        f16x8 bp2 = mk(c1[0], c1[1], c1[2],  c1[3],  c1[4],  c1[5],  c1[6],  c1[7]);
        f16x8 bp3 = mk(c1[8], c1[9], c1[10], c1[11], c1[12], c1[13], c1[14], c1[15]);

        // ---- O^T += V^T . P, 8 MFMA 32x32x16 ----
        {
            const int k0 = hi * 8;
            f16x8 av;
            av = ldb64x2(&vts[qcol][k0]);            oc0 = __builtin_amdgcn_mfma_f32_32x32x16_f16(av, bp0, oc0, 0, 0, 0);
            av = ldb64x2(&vts[qcol + 32][k0]);       oc1 = __builtin_amdgcn_mfma_f32_32x32x16_f16(av, bp0, oc1, 0, 0, 0);
            av = ldb64x2(&vts[qcol][k0 + 16]);       oc0 = __builtin_amdgcn_mfma_f32_32x32x16_f16(av, bp1, oc0, 0, 0, 0);
            av = ldb64x2(&vts[qcol + 32][k0 + 16]);  oc1 = __builtin_amdgcn_mfma_f32_32x32x16_f16(av, bp1, oc1, 0, 0, 0);
            av = ldb64x2(&vts[qcol][k0 + 32]);       oc0 = __builtin_amdgcn_mfma_f32_32x32x16_f16(av, bp2, oc0, 0, 0, 0);
            av = ldb64x2(&vts[qcol + 32][k0 + 32]);  oc1 = __builtin_amdgcn_mfma_f32_32x32x16_f16(av, bp2, oc1, 0, 0, 0);
            av = ldb64x2(&vts[qcol][k0 + 48]);       oc0 = __builtin_amdgcn_mfma_f32_32x32x16_f16(av, bp3, oc0, 0, 0, 0);
            av = ldb64x2(&vts[qcol + 32][k0 + 48]);  oc1 = __builtin_amdgcn_mfma_f32_32x32x16_f16(av, bp3, oc1, 0, 0, 0);
        }
    }

    // epilogue: O^T[d][q] regs -> z[b][s=q][h*64+d], scaled by 1/lrun
    float inv = 1.0f / lrun;
    size_t zb = ((size_t)b * SS + qt * 128 + w * 32 + qcol) * (size_t)(HH * DH) + h * DH;
    #pragma unroll
    for (int g = 0; g < 4; ++g) {
        f16x4 v0, v1;
        #pragma unroll
        for (int i = 0; i < 4; ++i) {
            v0[i] = (_Float16)(oc0[4 * g + i] * inv);
            v1[i] = (_Float16)(oc1[4 * g + i] * inv);
        }
        *reinterpret_cast<f16x4*>(z + zb + 8 * g + 4 * hi)      = v0;
        *reinterpret_cast<f16x4*>(z + zb + 32 + 8 * g + 4 * hi) = v1;
    }
}

// ---------------------------------------------------------------
// outproj: out[m][i] = sum_j wc[i][j] z[m][j]; z fp16, wc split fp16 2-term.
// grid 128, block 256.
// ---------------------------------------------------------------
__global__ __launch_bounds__(256) void outproj_kernel(
    const _Float16* __restrict__ z,
    const _Float16* __restrict__ wch, const _Float16* __restrict__ wcl,
    float* __restrict__ out)
{
    const int mt = blockIdx.x, m0 = mt * 64;
    __shared__ _Float16 zs[64][40], wh_[64][40], wl_[64][40];

    const int t = threadIdx.x;
    const int lane = t & 63, wid = t >> 6;
    const int fr = lane & 15, fg = lane >> 4, g8 = fg * 8;

    f32x4 acc[4];
    #pragma unroll
    for (int n = 0; n < 4; ++n) acc[n] = (f32x4){0.f, 0.f, 0.f, 0.f};

    for (int ks = 0; ks < DIN / 32; ++ks) {
        const int k0 = ks * 32;
        {
            int r = t >> 2, c8 = (t & 3) * 8;
            *reinterpret_cast<f16x8*>(&zs[r][c8]) =
                *reinterpret_cast<const f16x8*>(z + (size_t)(m0 + r) * DIN + k0 + c8);
            size_t wb = (size_t)r * DIN + k0 + c8;
            *reinterpret_cast<f16x8*>(&wh_[r][c8]) = *reinterpret_cast<const f16x8*>(wch + wb);
            *reinterpret_cast<f16x8*>(&wl_[r][c8]) = *reinterpret_cast<const f16x8*>(wcl + wb);
        }
        __syncthreads();
        f16x8 az = *reinterpret_cast<const f16x8*>(&zs[wid * 16 + fr][g8]);
        #pragma unroll
        for (int n = 0; n < 4; ++n) {
            f16x8 bh = *reinterpret_cast<const f16x8*>(&wh_[n * 16 + fr][g8]);
            f16x8 bl = *reinterpret_cast<const f16x8*>(&wl_[n * 16 + fr][g8]);
            acc[n] = __builtin_amdgcn_mfma_f32_16x16x32_f16(az, bh, acc[n], 0, 0, 0);
            acc[n] = __builtin_amdgcn_mfma_f32_16x16x32_f16(az, bl, acc[n], 0, 0, 0);
        }
        __syncthreads();
    }

    #pragma unroll
    for (int n = 0; n < 4; ++n)
        #pragma unroll
        for (int j = 0; j < 4; ++j) {
            int row = m0 + wid * 16 + fg * 4 + j;
            out[(size_t)row * DH + n * 16 + fr] = acc[n][j];
        }
}

extern "C" void kernel_launch(void* const* d_in, const int* in_sizes, int n_in,
                              void* d_out, int out_size, void* d_ws, size_t ws_size,
                              hipStream_t stream) {
    const float* x  = (const float*)d_in[0];
    const float* wq = (const float*)d_in[1];
    const float* wk = (const float*)d_in[2];
    const float* wv = (const float*)d_in[3];
    const float* wc = (const float*)d_in[4];
    float* out = (float*)d_out;

    const size_t wpl   = (size_t)3 * HH * 64 * DIN;     // 1,769,472
    const size_t plane = (size_t)BB * HH * SS * DH;     // 6,291,456
    _Float16* whi = (_Float16*)d_ws;
    _Float16* wlo = whi + wpl;
    _Float16* wch = wlo + wpl;
    _Float16* wcl = wch + (size_t)64 * DIN;
    _Float16* qh  = wcl + (size_t)64 * DIN;
    _Float16* ql  = qh + plane;
    _Float16* kh  = ql + plane;
    _Float16* kl  = kh + plane;
    _Float16* vt  = kl + plane;   // [b][h][d][s]
    _Float16* zz  = vt + plane;

    prep_w_kernel<<<dim3(12, HH, 3), 256, 0, stream>>>(wq, wk, wv, whi, wlo);
    prep_wc_kernel<<<24, 256, 0, stream>>>(wc, wch, wcl);
    qkv_proj_kernel<<<dim3(40, 128), 256, 0, stream>>>(x, whi, wlo, qh, ql, kh, kl, vt);
    attn_kernel<<<768, 256, 0, stream>>>(qh, ql, kh, kl, vt, zz);
    outproj_kernel<<<128, 256, 0, stream>>>(zz, wch, wcl, out);
}

// Round 9
// 258.731 us; speedup vs baseline: 11.2068x; 1.0570x over previous
//
#include <hip/hip_runtime.h>
#include <hip/hip_bf16.h>
#include <math.h>

#define BB 4
#define SS 2048
#define DIN 768
#define HH 12
#define DH 64
#define NT (SS / 64)

typedef __attribute__((ext_vector_type(8))) _Float16 f16x8;
typedef __attribute__((ext_vector_type(4))) _Float16 f16x4;
typedef __attribute__((ext_vector_type(2))) _Float16 f16x2;
typedef __attribute__((ext_vector_type(4))) float f32x4;
typedef __attribute__((ext_vector_type(16))) float f32x16;
typedef __attribute__((ext_vector_type(4))) unsigned u32x4;

// split fp32 -> fp16 hi + fp16 lo (v ~= hi+lo, |lo| <= 2^-11 |v|)
__device__ inline void splith(float v, _Float16& hi, _Float16& lo) {
    hi = (_Float16)v;
    lo = (_Float16)(v - (float)hi);
}
__device__ inline unsigned packh2(float a, float b) {
    f16x2 h; h[0] = (_Float16)a; h[1] = (_Float16)b;
    return __builtin_bit_cast(unsigned, h);
}
// 16B fp16 fragment via two 8B LDS reads (stride-68 rows are only 8B-aligned)
__device__ inline f16x8 ldb64x2(const _Float16* p) {
    const uint2* q = reinterpret_cast<const uint2*>(p);
    uint2 a = q[0], b = q[1];
    u32x4 u = {a.x, a.y, b.x, b.y};
    return __builtin_bit_cast(f16x8, u);
}
__device__ inline void stb64x2(_Float16* p, uint4 v) {
    uint2* q = reinterpret_cast<uint2*>(p);
    q[0] = make_uint2(v.x, v.y);
    q[1] = make_uint2(v.z, v.w);
}
__device__ inline f32x16 zero16() {
    f32x16 v;
    #pragma unroll
    for (int i = 0; i < 16; ++i) v[i] = 0.f;
    return v;
}

// ---------------------------------------------------------------
// prep_w: W[h][k][n] fp32 -> transposed+split planes whi/wlo[(which,h)][n][k] fp16
// grid (12 ktiles, 12 h, 3 which), block 256
// ---------------------------------------------------------------
__global__ __launch_bounds__(256) void prep_w_kernel(
    const float* __restrict__ wq, const float* __restrict__ wk, const float* __restrict__ wv,
    _Float16* __restrict__ whi, _Float16* __restrict__ wlo)
{
    const int kt = blockIdx.x, h = blockIdx.y, which = blockIdx.z;
    const float* w = (which == 0) ? wq : (which == 1) ? wk : wv;
    w += (size_t)h * (DIN * DH);
    const size_t plane = ((size_t)which * HH + h) * (size_t)(64 * DIN);

    __shared__ float tile[64][65];
    const int t = threadIdx.x;
    {
        int r = t >> 2, n0 = (t & 3) * 16;
        const float* src = w + (size_t)(kt * 64 + r) * DH + n0;
        #pragma unroll
        for (int q = 0; q < 4; ++q) {
            float4 v = *reinterpret_cast<const float4*>(src + q * 4);
            tile[r][n0 + q * 4 + 0] = v.x; tile[r][n0 + q * 4 + 1] = v.y;
            tile[r][n0 + q * 4 + 2] = v.z; tile[r][n0 + q * 4 + 3] = v.w;
        }
    }
    __syncthreads();
    {
        int n = t >> 2, k0 = (t & 3) * 16;
        f16x8 h0, h1, l0, l1;
        #pragma unroll
        for (int j = 0; j < 8; ++j) {
            _Float16 hh, ll;
            splith(tile[k0 + j][n], hh, ll);     h0[j] = hh; l0[j] = ll;
            splith(tile[k0 + 8 + j][n], hh, ll); h1[j] = hh; l1[j] = ll;
        }
        size_t base = plane + (size_t)n * DIN + kt * 64 + k0;
        *reinterpret_cast<f16x8*>(whi + base)     = h0;
        *reinterpret_cast<f16x8*>(whi + base + 8) = h1;
        *reinterpret_cast<f16x8*>(wlo + base)     = l0;
        *reinterpret_cast<f16x8*>(wlo + base + 8) = l1;
    }
}

// prep_wc: wc [64][768] fp32 -> wch/wcl fp16 (same layout). grid 24, block 256.
__global__ __launch_bounds__(256) void prep_wc_kernel(
    const float* __restrict__ wc,
    _Float16* __restrict__ wch, _Float16* __restrict__ wcl)
{
    int idx = (blockIdx.x * 256 + threadIdx.x) * 8;
    float4 a = *reinterpret_cast<const float4*>(wc + idx);
    float4 b = *reinterpret_cast<const float4*>(wc + idx + 4);
    float f[8] = {a.x, a.y, a.z, a.w, b.x, b.y, b.z, b.w};
    f16x8 hv, lv;
    #pragma unroll
    for (int j = 0; j < 8; ++j) {
        _Float16 hh, ll;
        splith(f[j], hh, ll);
        hv[j] = hh; lv[j] = ll;
    }
    *reinterpret_cast<f16x8*>(wch + idx) = hv;
    *reinterpret_cast<f16x8*>(wcl + idx) = lv;
}

// ---------------------------------------------------------------
// qkv_proj: x fp32 [8192][768] x Wsplit -> Q,K hi+lo fp16 [b][h][s][64],
// V fp16 TRANSPOSED [b][h][d][s].  3-term split MFMA.
// Q is pre-scaled by 0.125 (1/sqrt(64)) — exact under hi/lo split.
// Flat grid 4608 = 8 xcd x 16 mt-local x 36 planes. XCD remap pins an
// mt-SLICE (16 tiles = 3.1 MB of x) to each XCD -> x re-reads across the
// 36 planes hit that XCD's L2 instead of streaming 906 MB through L3.
// ---------------------------------------------------------------
__global__ __launch_bounds__(256) void qkv_proj_kernel(
    const float* __restrict__ x,
    const _Float16* __restrict__ whi, const _Float16* __restrict__ wlo,
    _Float16* __restrict__ qh, _Float16* __restrict__ ql,
    _Float16* __restrict__ kh, _Float16* __restrict__ kl,
    _Float16* __restrict__ vt)
{
    const int flat = blockIdx.x;
    const int xcd  = flat & 7;
    const int rest = flat >> 3;              // 0..575
    const int mt   = xcd * 16 + (rest & 15); // XCD owns contiguous 16-mt slice
    const int hw   = rest >> 4;              // 0..35, slow-varying per XCD
    const int which = hw / HH, h = hw % HH;
    const int m0 = mt * 64;
    const size_t wplane = ((size_t)which * HH + h) * (size_t)(64 * DIN);

    __shared__ _Float16 xsh[64][40], xsl[64][40], wsh[64][40], wsl[64][40];
    __shared__ _Float16 vtile[64][72];   // only used by which==2: [d][s_local]

    const int t = threadIdx.x;
    const int lane = t & 63, wid = t >> 6;
    const int fr = lane & 15, fg = lane >> 4, g8 = fg * 8;

    f32x4 acc[4];
    #pragma unroll
    for (int n = 0; n < 4; ++n) acc[n] = (f32x4){0.f, 0.f, 0.f, 0.f};

    for (int ks = 0; ks < DIN / 32; ++ks) {
        const int k0 = ks * 32;
        {
            int r = t >> 2, c8 = (t & 3) * 8;
            const float* xp = x + (size_t)(m0 + r) * DIN + k0 + c8;
            float4 a = *reinterpret_cast<const float4*>(xp);
            float4 b = *reinterpret_cast<const float4*>(xp + 4);
            float f[8] = {a.x, a.y, a.z, a.w, b.x, b.y, b.z, b.w};
            f16x8 xh, xl;
            #pragma unroll
            for (int j = 0; j < 8; ++j) {
                _Float16 hh, ll;
                splith(f[j], hh, ll);
                xh[j] = hh; xl[j] = ll;
            }
            *reinterpret_cast<f16x8*>(&xsh[r][c8]) = xh;
            *reinterpret_cast<f16x8*>(&xsl[r][c8]) = xl;
            size_t wb = wplane + (size_t)r * DIN + k0 + c8;
            *reinterpret_cast<f16x8*>(&wsh[r][c8]) = *reinterpret_cast<const f16x8*>(whi + wb);
            *reinterpret_cast<f16x8*>(&wsl[r][c8]) = *reinterpret_cast<const f16x8*>(wlo + wb);
        }
        __syncthreads();
        f16x8 ah = *reinterpret_cast<const f16x8*>(&xsh[wid * 16 + fr][g8]);
        f16x8 al = *reinterpret_cast<const f16x8*>(&xsl[wid * 16 + fr][g8]);
        #pragma unroll
        for (int n = 0; n < 4; ++n) {
            f16x8 bh = *reinterpret_cast<const f16x8*>(&wsh[n * 16 + fr][g8]);
            f16x8 bl = *reinterpret_cast<const f16x8*>(&wsl[n * 16 + fr][g8]);
            acc[n] = __builtin_amdgcn_mfma_f32_16x16x32_f16(ah, bh, acc[n], 0, 0, 0);
            acc[n] = __builtin_amdgcn_mfma_f32_16x16x32_f16(ah, bl, acc[n], 0, 0, 0);
            acc[n] = __builtin_amdgcn_mfma_f32_16x16x32_f16(al, bh, acc[n], 0, 0, 0);
        }
        __syncthreads();
    }

    if (which == 2) {
        // acc[n][j] = V[s_local = wid*16+fg*4+j][d = n*16+fr]
        #pragma unroll
        for (int n = 0; n < 4; ++n)
            #pragma unroll
            for (int j = 0; j < 4; ++j)
                vtile[n * 16 + fr][wid * 16 + fg * 4 + j] = (_Float16)acc[n][j];
        __syncthreads();
        int r = t >> 2, c0 = (t & 3) * 16;     // r = d, c0 = s_local
        int b0 = m0 >> 11, s0 = m0 & 2047;
        size_t base = (((size_t)b0 * HH + h) * DH + r) * SS + s0 + c0;
        *reinterpret_cast<uint4*>(vt + base)     = *reinterpret_cast<uint4*>(&vtile[r][c0]);
        *reinterpret_cast<uint4*>(vt + base + 8) = *reinterpret_cast<uint4*>(&vtile[r][c0 + 8]);
    } else {
        #pragma unroll
        for (int n = 0; n < 4; ++n)
            #pragma unroll
            for (int j = 0; j < 4; ++j) {
                int row = wid * 16 + fg * 4 + j;
                int m = m0 + row, bb = m >> 11, ss = m & 2047;
                size_t idx = (((size_t)bb * HH + h) * SS + ss) * DH + n * 16 + fr;
                float val = acc[n][j];
                if (which == 0) val *= 0.125f;   // fold 1/sqrt(D) into Q (exact pow2)
                _Float16 hi, lo;
                splith(val, hi, lo);
                if (which == 0) { qh[idx] = hi; ql[idx] = lo; }
                else            { kh[idx] = hi; kl[idx] = lo; }
            }
    }
}

// ---------------------------------------------------------------
// attn v2: 32x32x16 MFMA, swapped QK^T (S^T = K.Q^T), O^T = V^T.P.
// Block = 128 q-rows, 4 waves x 32 q-cols, kv tiles of 64.
// Softmax fully lane-local (lane owns one q-row; pair via shfl_xor 32).
// P stays in registers: packh2 + v_permlane32_swap -> PV B-frags.
// grid 768 (= 3 blocks/CU), XCD-chunk swizzled.
// ---------------------------------------------------------------
__global__ __launch_bounds__(256, 3) void attn_kernel(
    const _Float16* __restrict__ qhp, const _Float16* __restrict__ qlp,
    const _Float16* __restrict__ khp, const _Float16* __restrict__ klp,
    const _Float16* __restrict__ vtp,
    _Float16* __restrict__ z)
{
    const int flat = blockIdx.x;
    const int remap = (flat & 7) * 96 + (flat >> 3);   // bijective, 768 = 8*96
    const int qt = remap & 15;                          // 16 tiles of 128 q-rows
    const int h  = (remap >> 4) % HH;
    const int b  = remap / (16 * HH);

    const size_t headbase = ((size_t)b * HH + h) * (size_t)(SS * DH);
    const _Float16* Qh = qhp + headbase;
    const _Float16* Ql = qlp + headbase;
    const _Float16* Kh = khp + headbase;
    const _Float16* Kl = klp + headbase;
    const _Float16* Vt = vtp + headbase;   // [d][s]

    __shared__ _Float16 ksh[64][68], ksl[64][68], vts[64][68];

    const int t = threadIdx.x;
    const int lane = t & 63, w = t >> 6;
    const int qcol = lane & 31, hi = lane >> 5;
    const int r4 = t >> 2, c16 = (t & 3) * 16;

    // Q B-frags (B[k=d][n=q]): lane holds Q[q = qt*128 + w*32 + qcol][d = hi*8 + j + 16ks]
    const size_t qbase = (size_t)(qt * 128 + w * 32 + qcol) * DH + hi * 8;
    f16x8 bqh[4], bql[4];
    #pragma unroll
    for (int ks = 0; ks < 4; ++ks) {
        bqh[ks] = *reinterpret_cast<const f16x8*>(Qh + qbase + 16 * ks);
        bql[ks] = *reinterpret_cast<const f16x8*>(Ql + qbase + 16 * ks);
    }

    uint4 rk0, rk1, rl0, rl1, rv0, rv1;
    auto prefetch = [&](int kt) {
        size_t sk = (size_t)(kt * 64 + r4) * DH + c16;
        rk0 = *reinterpret_cast<const uint4*>(Kh + sk);
        rk1 = *reinterpret_cast<const uint4*>(Kh + sk + 8);
        rl0 = *reinterpret_cast<const uint4*>(Kl + sk);
        rl1 = *reinterpret_cast<const uint4*>(Kl + sk + 8);
        size_t sv = (size_t)r4 * SS + kt * 64 + c16;
        rv0 = *reinterpret_cast<const uint4*>(Vt + sv);
        rv1 = *reinterpret_cast<const uint4*>(Vt + sv + 8);
    };
    prefetch(0);

    float mrun = -INFINITY, lrun = 0.f;    // per-lane: lane owns q-row qcol
    f32x16 oc0 = zero16(), oc1 = zero16(); // O^T: d 0-31 / d 32-63, col = q

    for (int kt = 0; kt < NT; ++kt) {
        __syncthreads();   // prior compute done reading ksh/ksl/vts
        stb64x2(&ksh[r4][c16],     rk0);
        stb64x2(&ksh[r4][c16 + 8], rk1);
        stb64x2(&ksl[r4][c16],     rl0);
        stb64x2(&ksl[r4][c16 + 8], rl1);
        stb64x2(&vts[r4][c16],     rv0);
        stb64x2(&vts[r4][c16 + 8], rv1);
        if (kt + 1 < NT) prefetch(kt + 1);
        __syncthreads();   // tile ready

        // ---- S^T = K.Q^T  (kh*qh + kh*ql + kl*qh), 24 MFMA 32x32x16 ----
        f32x16 c0 = zero16(), c1 = zero16();   // kv 0-31 / kv 32-63, col = q
        #pragma unroll
        for (int ks = 0; ks < 4; ++ks) {
            const int doff = hi * 8 + 16 * ks;
            f16x8 a0h = ldb64x2(&ksh[qcol][doff]);
            f16x8 a0l = ldb64x2(&ksl[qcol][doff]);
            c0 = __builtin_amdgcn_mfma_f32_32x32x16_f16(a0h, bqh[ks], c0, 0, 0, 0);
            c0 = __builtin_amdgcn_mfma_f32_32x32x16_f16(a0h, bql[ks], c0, 0, 0, 0);
            c0 = __builtin_amdgcn_mfma_f32_32x32x16_f16(a0l, bqh[ks], c0, 0, 0, 0);
            f16x8 a1h = ldb64x2(&ksh[qcol + 32][doff]);
            f16x8 a1l = ldb64x2(&ksl[qcol + 32][doff]);
            c1 = __builtin_amdgcn_mfma_f32_32x32x16_f16(a1h, bqh[ks], c1, 0, 0, 0);
            c1 = __builtin_amdgcn_mfma_f32_32x32x16_f16(a1h, bql[ks], c1, 0, 0, 0);
            c1 = __builtin_amdgcn_mfma_f32_32x32x16_f16(a1l, bqh[ks], c1, 0, 0, 0);
        }

        // ---- softmax: lane-local over its q-row (scores pre-scaled) ----
        float mx = c0[0];
        #pragma unroll
        for (int i = 1; i < 16; ++i) mx = fmaxf(mx, c0[i]);
        #pragma unroll
        for (int i = 0; i < 16; ++i) mx = fmaxf(mx, c1[i]);
        mx = fmaxf(mx, __shfl_xor(mx, 32));
        float nm = fmaxf(mrun, mx);
        float corr = __expf(mrun - nm);
        float sum = 0.f;
        #pragma unroll
        for (int i = 0; i < 16; ++i) { float p = __expf(c0[i] - nm); c0[i] = p; sum += p; }
        #pragma unroll
        for (int i = 0; i < 16; ++i) { float p = __expf(c1[i] - nm); c1[i] = p; sum += p; }
        sum += __shfl_xor(sum, 32);
        lrun = lrun * corr + sum;
        mrun = nm;
        #pragma unroll
        for (int i = 0; i < 16; ++i) { oc0[i] *= corr; oc1[i] *= corr; }

        // ---- P -> PV B-frags in registers (packh2 + permlane32_swap) ----
        auto mk = [](float s0, float s1, float s2, float s3,
                     float s4, float s5, float s6, float s7) -> f16x8 {
            unsigned a0 = packh2(s0, s1), a1 = packh2(s2, s3);
            unsigned b0 = packh2(s4, s5), b1 = packh2(s6, s7);
            asm volatile("v_permlane32_swap_b32 %0, %1" : "+v"(a0), "+v"(b0));
            asm volatile("v_permlane32_swap_b32 %0, %1" : "+v"(a1), "+v"(b1));
            u32x4 u = {a0, a1, b0, b1};
            return __builtin_bit_cast(f16x8, u);
        };
        f16x8 bp0 = mk(c0[0], c0[1], c0[2],  c0[3],  c0[4],  c0[5],  c0[6],  c0[7]);
        f16x8 bp1 = mk(c0[8], c0[9], c0[10], c0[11], c0[12], c0[13], c0[14], c0[15]);
        f16x8 bp2 = mk(c1[0], c1[1], c1[2],  c1[3],  c1[4],  c1[5],  c1[6],  c1[7]);
        f16x8 bp3 = mk(c1[8], c1[9], c1[10], c1[11], c1[12], c1[13], c1[14], c1[15]);

        // ---- O^T += V^T . P, 8 MFMA 32x32x16 ----
        {
            const int k0 = hi * 8;
            f16x8 av;
            av = ldb64x2(&vts[qcol][k0]);            oc0 = __builtin_amdgcn_mfma_f32_32x32x16_f16(av, bp0, oc0, 0, 0, 0);
            av = ldb64x2(&vts[qcol + 32][k0]);       oc1 = __builtin_amdgcn_mfma_f32_32x32x16_f16(av, bp0, oc1, 0, 0, 0);
            av = ldb64x2(&vts[qcol][k0 + 16]);       oc0 = __builtin_amdgcn_mfma_f32_32x32x16_f16(av, bp1, oc0, 0, 0, 0);
            av = ldb64x2(&vts[qcol + 32][k0 + 16]);  oc1 = __builtin_amdgcn_mfma_f32_32x32x16_f16(av, bp1, oc1, 0, 0, 0);
            av = ldb64x2(&vts[qcol][k0 + 32]);       oc0 = __builtin_amdgcn_mfma_f32_32x32x16_f16(av, bp2, oc0, 0, 0, 0);
            av = ldb64x2(&vts[qcol + 32][k0 + 32]);  oc1 = __builtin_amdgcn_mfma_f32_32x32x16_f16(av, bp2, oc1, 0, 0, 0);
            av = ldb64x2(&vts[qcol][k0 + 48]);       oc0 = __builtin_amdgcn_mfma_f32_32x32x16_f16(av, bp3, oc0, 0, 0, 0);
            av = ldb64x2(&vts[qcol + 32][k0 + 48]);  oc1 = __builtin_amdgcn_mfma_f32_32x32x16_f16(av, bp3, oc1, 0, 0, 0);
        }
    }

    // epilogue: O^T[d][q] regs -> z[b][s=q][h*64+d], scaled by 1/lrun
    float inv = 1.0f / lrun;
    size_t zb = ((size_t)b * SS + qt * 128 + w * 32 + qcol) * (size_t)(HH * DH) + h * DH;
    #pragma unroll
    for (int g = 0; g < 4; ++g) {
        f16x4 v0, v1;
        #pragma unroll
        for (int i = 0; i < 4; ++i) {
            v0[i] = (_Float16)(oc0[4 * g + i] * inv);
            v1[i] = (_Float16)(oc1[4 * g + i] * inv);
        }
        *reinterpret_cast<f16x4*>(z + zb + 8 * g + 4 * hi)      = v0;
        *reinterpret_cast<f16x4*>(z + zb + 32 + 8 * g + 4 * hi) = v1;
    }
}

// ---------------------------------------------------------------
// outproj: out[m][i] = sum_j wc[i][j] z[m][j]; z fp16, wc split fp16 2-term.
// grid 128, block 256.
// ---------------------------------------------------------------
__global__ __launch_bounds__(256) void outproj_kernel(
    const _Float16* __restrict__ z,
    const _Float16* __restrict__ wch, const _Float16* __restrict__ wcl,
    float* __restrict__ out)
{
    const int mt = blockIdx.x, m0 = mt * 64;
    __shared__ _Float16 zs[64][40], wh_[64][40], wl_[64][40];

    const int t = threadIdx.x;
    const int lane = t & 63, wid = t >> 6;
    const int fr = lane & 15, fg = lane >> 4, g8 = fg * 8;

    f32x4 acc[4];
    #pragma unroll
    for (int n = 0; n < 4; ++n) acc[n] = (f32x4){0.f, 0.f, 0.f, 0.f};

    for (int ks = 0; ks < DIN / 32; ++ks) {
        const int k0 = ks * 32;
        {
            int r = t >> 2, c8 = (t & 3) * 8;
            *reinterpret_cast<f16x8*>(&zs[r][c8]) =
                *reinterpret_cast<const f16x8*>(z + (size_t)(m0 + r) * DIN + k0 + c8);
            size_t wb = (size_t)r * DIN + k0 + c8;
            *reinterpret_cast<f16x8*>(&wh_[r][c8]) = *reinterpret_cast<const f16x8*>(wch + wb);
            *reinterpret_cast<f16x8*>(&wl_[r][c8]) = *reinterpret_cast<const f16x8*>(wcl + wb);
        }
        __syncthreads();
        f16x8 az = *reinterpret_cast<const f16x8*>(&zs[wid * 16 + fr][g8]);
        #pragma unroll
        for (int n = 0; n < 4; ++n) {
            f16x8 bh = *reinterpret_cast<const f16x8*>(&wh_[n * 16 + fr][g8]);
            f16x8 bl = *reinterpret_cast<const f16x8*>(&wl_[n * 16 + fr][g8]);
            acc[n] = __builtin_amdgcn_mfma_f32_16x16x32_f16(az, bh, acc[n], 0, 0, 0);
            acc[n] = __builtin_amdgcn_mfma_f32_16x16x32_f16(az, bl, acc[n], 0, 0, 0);
        }
        __syncthreads();
    }

    #pragma unroll
    for (int n = 0; n < 4; ++n)
        #pragma unroll
        for (int j = 0; j < 4; ++j) {
            int row = m0 + wid * 16 + fg * 4 + j;
            out[(size_t)row * DH + n * 16 + fr] = acc[n][j];
        }
}

extern "C" void kernel_launch(void* const* d_in, const int* in_sizes, int n_in,
                              void* d_out, int out_size, void* d_ws, size_t ws_size,
                              hipStream_t stream) {
    const float* x  = (const float*)d_in[0];
    const float* wq = (const float*)d_in[1];
    const float* wk = (const float*)d_in[2];
    const float* wv = (const float*)d_in[3];
    const float* wc = (const float*)d_in[4];
    float* out = (float*)d_out;

    const size_t wpl   = (size_t)3 * HH * 64 * DIN;     // 1,769,472
    const size_t plane = (size_t)BB * HH * SS * DH;     // 6,291,456
    _Float16* whi = (_Float16*)d_ws;
    _Float16* wlo = whi + wpl;
    _Float16* wch = wlo + wpl;
    _Float16* wcl = wch + (size_t)64 * DIN;
    _Float16* qh  = wcl + (size_t)64 * DIN;
    _Float16* ql  = qh + plane;
    _Float16* kh  = ql + plane;
    _Float16* kl  = kh + plane;
    _Float16* vt  = kl + plane;   // [b][h][d][s]
    _Float16* zz  = vt + plane;

    prep_w_kernel<<<dim3(12, HH, 3), 256, 0, stream>>>(wq, wk, wv, whi, wlo);
    prep_wc_kernel<<<24, 256, 0, stream>>>(wc, wch, wcl);
    qkv_proj_kernel<<<4608, 256, 0, stream>>>(x, whi, wlo, qh, ql, kh, kl, vt);
    attn_kernel<<<768, 256, 0, stream>>>(qh, ql, kh, kl, vt, zz);
    outproj_kernel<<<128, 256, 0, stream>>>(zz, wch, wcl, out);
}